// Round 1
// baseline (2127.597 us; speedup 1.0000x reference)
//
#include <hip/hip_runtime.h>
#include <math.h>

constexpr int cB = 128;
constexpr int cK = 51;
constexpr int cL = 60;
constexpr int cH = 32;
constexpr int cC = 60;           // L*D
constexpr int cKL = 3060;        // K*L
constexpr int cKL32 = 97920;     // K*L*32
constexpr float kLOG2PI = 1.8378770664093453f;

__device__ __forceinline__ float fsig(float x) { return 1.0f / (1.0f + __expf(-x)); }
__device__ __forceinline__ float ftanh(float x) {
  float e = __expf(2.0f * x);
  return 1.0f - 2.0f / (e + 1.0f);
}

// ---------------- q/k projections: rows = B*K = 6528, 8 rows/block ----------------
__global__ __launch_bounds__(256) void qk_kernel(
    const float* __restrict__ x, const float* __restrict__ Wq, const float* __restrict__ bq,
    const float* __restrict__ Wk, const float* __restrict__ bk,
    float* __restrict__ q, float* __restrict__ kx) {
  __shared__ float xs[8][cC];
  const int row0 = blockIdx.x * 8;
  const int tid = threadIdx.x;
  for (int idx = tid; idx < 8 * cC; idx += 256) {
    int lr = idx / cC, t = idx % cC;
    xs[lr][t] = x[(row0 + lr) * cC + t];
  }
  __syncthreads();
  for (int idx = tid; idx < 8 * 2 * cC; idx += 256) {
    int col = idx % cC;
    int r2 = idx / cC;
    int m = r2 & 1, lr = r2 >> 1;
    const float* W = m ? Wk : Wq;
    float acc = m ? bk[col] : bq[col];
    #pragma unroll 4
    for (int t = 0; t < cC; ++t) acc += xs[lr][t] * W[t * cC + col];
    float* outp = m ? kx : q;
    outp[(row0 + lr) * cC + col] = acc;
  }
}

// ---------------- score = q @ reshape(k) / sqrt(60); softmax over axis=1 ----------------
__global__ __launch_bounds__(256) void attn_kernel(
    const float* __restrict__ q, const float* __restrict__ kx, float* __restrict__ graph) {
  __shared__ float qb[cKL];
  __shared__ float kb[cKL];
  __shared__ float sc[cK * cK];
  __shared__ float cmax[cK], csum[cK];
  const int b = blockIdx.x;
  const int tid = threadIdx.x;
  for (int idx = tid; idx < cKL; idx += 256) {
    qb[idx] = q[b * cKL + idx];
    kb[idx] = kx[b * cKL + idx];
  }
  __syncthreads();
  const float scale = 1.0f / sqrtf(60.0f);
  for (int idx = tid; idx < cK * cK; idx += 256) {
    int i = idx / cK, j = idx % cK;
    float acc = 0.0f;
    #pragma unroll 4
    for (int t = 0; t < cC; ++t) acc += qb[i * cC + t] * kb[t * cK + j];
    sc[idx] = acc * scale;
  }
  __syncthreads();
  if (tid < cK) {
    float m = -1e30f;
    for (int i = 0; i < cK; ++i) m = fmaxf(m, sc[i * cK + tid]);
    float ssum = 0.0f;
    for (int i = 0; i < cK; ++i) ssum += __expf(sc[i * cK + tid] - m);
    cmax[tid] = m; csum[tid] = ssum;
  }
  __syncthreads();
  for (int idx = tid; idx < cK * cK; idx += 256) {
    int j = idx % cK;
    graph[b * cK * cK + idx] = __expf(sc[idx] - cmax[j]) / csum[j];
  }
}

// ---------------- LSTM: one wave (64 lanes) per sequence, 4 sequences/block ----------------
// lane j holds Whh rows j and j+64 in registers. Lanes 0..31 own h,c.
// Row mapping: z[0:32]=i (lanes 0..31 acc0), z[32:64]=f (lanes 32..63 acc0),
//              z[64:96]=g (lanes 0..31 acc1), z[96:128]=o (lanes 32..63 acc1).
__global__ __launch_bounds__(256) void lstm_kernel(
    const float* __restrict__ x, const float* __restrict__ Wih, const float* __restrict__ Whh,
    const float* __restrict__ bih, const float* __restrict__ bhh, float* __restrict__ hout) {
  const int wave = threadIdx.x >> 6;
  const int lane = threadIdx.x & 63;
  const int seq = blockIdx.x * 4 + wave;   // < 6528
  const int j = lane;
  float w0[32], w1[32];
  #pragma unroll
  for (int k2 = 0; k2 < 32; ++k2) {
    w0[k2] = Whh[j * 32 + k2];
    w1[k2] = Whh[(j + 64) * 32 + k2];
  }
  const float wi0 = Wih[j], wi1 = Wih[j + 64];
  const float bb0 = bih[j] + bhh[j];
  const float bb1 = bih[j + 64] + bhh[j + 64];
  const float xr = (lane < cL) ? x[seq * cL + lane] : 0.0f;
  float h = 0.0f, c = 0.0f;
  float* outp = hout + (size_t)seq * cL * cH;
  for (int t = 0; t < cL; ++t) {
    const float xt = __shfl(xr, t);
    float a0 = bb0 + wi0 * xt;
    float a1 = bb1 + wi1 * xt;
    #pragma unroll
    for (int k2 = 0; k2 < 32; ++k2) {
      const float hk = __shfl(h, k2);
      a0 += w0[k2] * hk;
      a1 += w1[k2] * hk;
    }
    const float sA = fsig(a0);     // lanes<32: sig(i); lanes>=32: sig(f)
    const float sB = fsig(a1);     // lanes>=32: sig(o)
    const float tB = ftanh(a1);    // lanes<32: tanh(g)
    const float p = sA * tB;
    const float sf = __shfl(sA, (lane & 31) + 32);
    const float so = __shfl(sB, (lane & 31) + 32);
    c = sf * c + p;
    h = so * ftanh(c);
    if (lane < 32) outp[t * cH + lane] = h;
  }
}

// ---------------- einsum('bkld,bkj->bjld') + GNN, fused per (b,l) ----------------
__global__ __launch_bounds__(256) void gnn_kernel(
    const float* __restrict__ hbuf, const float* __restrict__ graph,
    const float* __restrict__ Wn, const float* __restrict__ bn_,
    const float* __restrict__ Wr, const float* __restrict__ W2,
    const float* __restrict__ b2, float* __restrict__ out) {
  __shared__ float g[cK * cK];
  __shared__ __align__(16) float hl[cK][cH];
  __shared__ __align__(16) float hm[cK][cH];
  __shared__ __align__(16) float agg[cK][cH];
  __shared__ __align__(16) float rl[cK][cH];
  __shared__ __align__(16) float wn[cH * cH];
  __shared__ __align__(16) float wr[cH * cH];
  __shared__ __align__(16) float w2[cH * cH];
  __shared__ float bnb[cH], b2b[cH];
  const int l = blockIdx.x;
  const int b = blockIdx.y;
  const int tid = threadIdx.x;
  for (int idx = tid; idx < cK * cK; idx += 256) g[idx] = graph[b * cK * cK + idx];
  for (int idx = tid; idx < cH * cH; idx += 256) { wn[idx] = Wn[idx]; wr[idx] = Wr[idx]; w2[idx] = W2[idx]; }
  if (tid < cH) { bnb[tid] = bn_[tid]; b2b[tid] = b2[tid]; }
  const float* hb = hbuf + (size_t)b * cK * cL * cH;
  for (int idx = tid; idx < cK * cH; idx += 256) {
    int kk = idx >> 5, d = idx & 31;
    hl[kk][d] = hb[(kk * cL + l) * cH + d];
    hm[kk][d] = (l > 0) ? hb[(kk * cL + (l - 1)) * cH + d] : 0.0f;
  }
  __syncthreads();
  const int jp = tid >> 3;          // unit: 2 j's x 4 d's; active jp < 26
  const int dq = tid & 7;
  const int j0 = jp * 2, d0 = dq * 4;
  const bool act = (jp < 26);
  const bool has1 = (j0 + 1 < cK);
  // phase 1: agg[j][d] = sum_k g[k][j] * hl[k][d]
  if (act) {
    float a0[4] = {0, 0, 0, 0}, a1[4] = {0, 0, 0, 0};
    for (int kk = 0; kk < cK; ++kk) {
      const float g0 = g[kk * cK + j0];
      const float g1 = has1 ? g[kk * cK + j0 + 1] : 0.0f;
      const float4 hv = *reinterpret_cast<const float4*>(&hl[kk][d0]);
      a0[0] += g0 * hv.x; a0[1] += g0 * hv.y; a0[2] += g0 * hv.z; a0[3] += g0 * hv.w;
      a1[0] += g1 * hv.x; a1[1] += g1 * hv.y; a1[2] += g1 * hv.z; a1[3] += g1 * hv.w;
    }
    #pragma unroll
    for (int dd = 0; dd < 4; ++dd) {
      agg[j0][d0 + dd] = a0[dd];
      if (has1) agg[j0 + 1][d0 + dd] = a1[dd];
    }
  }
  __syncthreads();
  // phase 2: rl = relu(bn + agg@Wn + hm@Wr)
  if (act) {
    float r0v[4], r1v[4];
    #pragma unroll
    for (int dd = 0; dd < 4; ++dd) { r0v[dd] = bnb[d0 + dd]; r1v[dd] = bnb[d0 + dd]; }
    for (int e = 0; e < cH; ++e) {
      const float ag0 = agg[j0][e], hh0 = hm[j0][e];
      const float ag1 = has1 ? agg[j0 + 1][e] : 0.0f;
      const float hh1 = has1 ? hm[j0 + 1][e] : 0.0f;
      const float4 wnv = *reinterpret_cast<const float4*>(&wn[e * cH + d0]);
      const float4 wrv = *reinterpret_cast<const float4*>(&wr[e * cH + d0]);
      r0v[0] += ag0 * wnv.x + hh0 * wrv.x; r0v[1] += ag0 * wnv.y + hh0 * wrv.y;
      r0v[2] += ag0 * wnv.z + hh0 * wrv.z; r0v[3] += ag0 * wnv.w + hh0 * wrv.w;
      r1v[0] += ag1 * wnv.x + hh1 * wrv.x; r1v[1] += ag1 * wnv.y + hh1 * wrv.y;
      r1v[2] += ag1 * wnv.z + hh1 * wrv.z; r1v[3] += ag1 * wnv.w + hh1 * wrv.w;
    }
    #pragma unroll
    for (int dd = 0; dd < 4; ++dd) {
      rl[j0][d0 + dd] = fmaxf(r0v[dd], 0.0f);
      if (has1) rl[j0 + 1][d0 + dd] = fmaxf(r1v[dd], 0.0f);
    }
  }
  __syncthreads();
  // phase 3: out = rl @ W2 + b2  (h_gcn_pre, written to d_out's h_gcn region)
  if (act) {
    float o0[4], o1[4];
    #pragma unroll
    for (int dd = 0; dd < 4; ++dd) { o0[dd] = b2b[d0 + dd]; o1[dd] = b2b[d0 + dd]; }
    for (int e = 0; e < cH; ++e) {
      const float rr0 = rl[j0][e];
      const float rr1 = has1 ? rl[j0 + 1][e] : 0.0f;
      const float4 w2v = *reinterpret_cast<const float4*>(&w2[e * cH + d0]);
      o0[0] += rr0 * w2v.x; o0[1] += rr0 * w2v.y; o0[2] += rr0 * w2v.z; o0[3] += rr0 * w2v.w;
      o1[0] += rr1 * w2v.x; o1[1] += rr1 * w2v.y; o1[2] += rr1 * w2v.z; o1[3] += rr1 * w2v.w;
    }
    size_t base0 = (((size_t)b * cK + j0) * cL + l) * cH + d0;
    #pragma unroll
    for (int dd = 0; dd < 4; ++dd) out[base0 + dd] = o0[dd];
    if (has1) {
      size_t base1 = (((size_t)b * cK + j0 + 1) * cL + l) * cH + d0;
      #pragma unroll
      for (int dd = 0; dd < 4; ++dd) out[base1 + dd] = o1[dd];
    }
  }
}

// ---------------- generic small MLP layer: out = bn(relu(A@W + bias)) ----------------
// A: 128 x Kd, W: Kd x N, out: 128 x N. Block covers 8 cols; thread: 4 rows x 1 col.
__global__ __launch_bounds__(256) void mlp_kernel(
    const float* __restrict__ A, int Kd, const float* __restrict__ W, int N,
    const float* __restrict__ bias, const float* __restrict__ gg,
    const float* __restrict__ bb, const float* __restrict__ mm,
    const float* __restrict__ vv, float* __restrict__ outz) {
  __shared__ float At[128][65];
  __shared__ float Wt[64][8];
  const int tid = threadIdx.x;
  const int c = tid & 7, rg = tid >> 3;
  const int col = blockIdx.x * 8 + c;
  float acc[4] = {0, 0, 0, 0};
  for (int k0 = 0; k0 < Kd; k0 += 64) {
    const int kt = min(64, Kd - k0);
    for (int idx = tid; idx < 128 * 64; idx += 256) {
      int r = idx >> 6, kk = idx & 63;
      At[r][kk] = (kk < kt) ? A[r * Kd + k0 + kk] : 0.0f;
    }
    for (int idx = tid; idx < 64 * 8; idx += 256) {
      int kk = idx >> 3, cc2 = idx & 7;
      int col2 = blockIdx.x * 8 + cc2;
      Wt[kk][cc2] = (kk < kt && col2 < N) ? W[(k0 + kk) * N + col2] : 0.0f;
    }
    __syncthreads();
    #pragma unroll 4
    for (int kk = 0; kk < 64; ++kk) {
      const float w = Wt[kk][c];
      #pragma unroll
      for (int i = 0; i < 4; ++i) acc[i] += At[rg * 4 + i][kk] * w;
    }
    __syncthreads();
  }
  if (col < N) {
    const float inv = rsqrtf(vv[col] + 1e-5f) * gg[col];
    #pragma unroll
    for (int i = 0; i < 4; ++i) {
      int r = rg * 4 + i;
      float z = fmaxf(acc[i] + bias[col], 0.0f);
      outz[r * N + col] = (z - mm[col]) * inv + bb[col];
    }
  }
}

// ---------------- big GEMM: d_out.h_gcn = z2 @ W3 + b3 + h_gcn_pre (RMW) ----------------
// Block: 128 rows x 64 cols, K=500 in tiles of 50. Thread: 8 rows x 4 cols.
__global__ __launch_bounds__(256) void w3_kernel(
    const float* __restrict__ z2, const float* __restrict__ W3,
    const float* __restrict__ b3, float* __restrict__ outh) {
  __shared__ __align__(16) float At[128][52];
  __shared__ __align__(16) float Wt[50][64];
  const int tid = threadIdx.x;
  const int n0 = blockIdx.x * 64;
  const int cg = tid & 15, rg = tid >> 4;
  const int c0 = cg * 4, r0 = rg * 8;
  float acc[8][4];
  #pragma unroll
  for (int i = 0; i < 8; ++i)
    #pragma unroll
    for (int jj = 0; jj < 4; ++jj) acc[i][jj] = 0.0f;
  for (int k0 = 0; k0 < 500; k0 += 50) {
    for (int idx = tid; idx < 128 * 50; idx += 256) {
      int r = idx / 50, kk = idx % 50;
      At[r][kk] = z2[r * 500 + k0 + kk];
    }
    for (int idx = tid; idx < 50 * 64; idx += 256) {
      int kk = idx >> 6, cc2 = idx & 63;
      Wt[kk][cc2] = W3[(size_t)(k0 + kk) * cKL32 + n0 + cc2];
    }
    __syncthreads();
    for (int kk = 0; kk < 50; kk += 2) {
      const float4 wv0 = *reinterpret_cast<const float4*>(&Wt[kk][c0]);
      const float4 wv1 = *reinterpret_cast<const float4*>(&Wt[kk + 1][c0]);
      #pragma unroll
      for (int i = 0; i < 8; ++i) {
        const float2 av = *reinterpret_cast<const float2*>(&At[r0 + i][kk]);
        acc[i][0] += av.x * wv0.x + av.y * wv1.x;
        acc[i][1] += av.x * wv0.y + av.y * wv1.y;
        acc[i][2] += av.x * wv0.z + av.y * wv1.z;
        acc[i][3] += av.x * wv0.w + av.y * wv1.w;
      }
    }
    __syncthreads();
  }
  #pragma unroll
  for (int i = 0; i < 8; ++i) {
    const int r = r0 + i;
    const size_t base = (size_t)r * cKL32 + n0 + c0;
    #pragma unroll
    for (int jj = 0; jj < 4; ++jj) {
      const int n = n0 + c0 + jj;
      outh[base + jj] = acc[i][jj] + b3[n] + outh[base + jj];
    }
  }
}

// ---------------- ann GEMM split-K: partial[blk] = h_gcn[:, kchunk] @ annW[kchunk, :] ----------------
// 255 blocks, K-chunk 384 (12 subtiles of 32). Block: 128 rows x 128 cols (100 real).
__global__ __launch_bounds__(256) void ann_kernel(
    const float* __restrict__ hg, const float* __restrict__ annW, float* __restrict__ partial) {
  __shared__ __align__(16) float At[128][34];
  __shared__ __align__(16) float Wt[32][128];
  const int tid = threadIdx.x;
  const int bx = blockIdx.x;   // 255
  const int k0 = bx * 384;
  const int cg = tid & 15, rg = tid >> 4;
  const int c0 = cg * 8, r0 = rg * 8;
  float acc[8][8];
  #pragma unroll
  for (int i = 0; i < 8; ++i)
    #pragma unroll
    for (int jj = 0; jj < 8; ++jj) acc[i][jj] = 0.0f;
  for (int st = 0; st < 12; ++st) {
    const int kb = k0 + st * 32;
    for (int idx = tid; idx < 128 * 32; idx += 256) {
      int r = idx >> 5, kk = idx & 31;
      At[r][kk] = hg[(size_t)r * cKL32 + kb + kk];
    }
    for (int idx = tid; idx < 32 * 128; idx += 256) {
      int kk = idx >> 7, cc2 = idx & 127;
      Wt[kk][cc2] = (cc2 < 100) ? annW[(size_t)(kb + kk) * 100 + cc2] : 0.0f;
    }
    __syncthreads();
    for (int kk = 0; kk < 32; kk += 2) {
      const float4 w00 = *reinterpret_cast<const float4*>(&Wt[kk][c0]);
      const float4 w01 = *reinterpret_cast<const float4*>(&Wt[kk][c0 + 4]);
      const float4 w10 = *reinterpret_cast<const float4*>(&Wt[kk + 1][c0]);
      const float4 w11 = *reinterpret_cast<const float4*>(&Wt[kk + 1][c0 + 4]);
      #pragma unroll
      for (int i = 0; i < 8; ++i) {
        const float2 av = *reinterpret_cast<const float2*>(&At[r0 + i][kk]);
        acc[i][0] += av.x * w00.x + av.y * w10.x;
        acc[i][1] += av.x * w00.y + av.y * w10.y;
        acc[i][2] += av.x * w00.z + av.y * w10.z;
        acc[i][3] += av.x * w00.w + av.y * w10.w;
        acc[i][4] += av.x * w01.x + av.y * w11.x;
        acc[i][5] += av.x * w01.y + av.y * w11.y;
        acc[i][6] += av.x * w01.z + av.y * w11.z;
        acc[i][7] += av.x * w01.w + av.y * w11.w;
      }
    }
    __syncthreads();
  }
  #pragma unroll
  for (int i = 0; i < 8; ++i) {
    #pragma unroll
    for (int jj = 0; jj < 8; ++jj) {
      const int cc = c0 + jj;
      if (cc < 100) partial[(size_t)bx * 12800 + (r0 + i) * 100 + cc] = acc[i][jj];
    }
  }
}

// ---------------- reduce split-K partials + bias + relu + bn -> hid ----------------
__global__ __launch_bounds__(256) void annred_kernel(
    const float* __restrict__ partial, const float* __restrict__ ab,
    const float* __restrict__ gg, const float* __restrict__ bb,
    const float* __restrict__ mm, const float* __restrict__ vv, float* __restrict__ hid) {
  const int oi = blockIdx.x * 256 + threadIdx.x;   // < 12800
  if (oi < 12800) {
    float s = 0.0f;
    for (int p = 0; p < 255; ++p) s += partial[(size_t)p * 12800 + oi];
    const int c = oi % 100;
    const float z = fmaxf(s + ab[c], 0.0f);
    hid[oi] = (z - mm[c]) * rsqrtf(vv[c] + 1e-5f) * gg[c] + bb[c];
  }
}

// ---------------- log_prob: MAF collapses to u = a*x + b (mask_out is all zeros) ----------------
__global__ __launch_bounds__(256) void logp_kernel(
    const float* __restrict__ x, const float* __restrict__ mob,
    const float* __restrict__ mlg, const float* __restrict__ mbeta, float* __restrict__ lp) {
  const int b = blockIdx.x;
  const int tid = threadIdx.x;
  const float rs = rsqrtf(1.0f + 1e-5f);
  const float A0 = __expf(mlg[0] - mob[1]) * rs;
  const float B0 = -mob[0] * __expf(-mob[1]) * __expf(mlg[0]) * rs + mbeta[0];
  const float A1 = __expf(mlg[1] - mob[3]) * rs;
  const float B1 = -mob[2] * __expf(-mob[3]) * __expf(mlg[1]) * rs + mbeta[1];
  const float S = (mlg[0] - mob[1]) + (mlg[1] - mob[3]) - logf(1.0f + 1e-5f);
  const float a = A1 * A0;
  const float bc = A1 * B0 + B1;
  float s = 0.0f;
  for (int t = tid; t < cKL; t += 256) {
    const float u = a * x[b * cKL + t] + bc;
    s += u * u;
  }
  #pragma unroll
  for (int off = 32; off > 0; off >>= 1) s += __shfl_down(s, off);
  __shared__ float red[4];
  if ((tid & 63) == 0) red[tid >> 6] = s;
  __syncthreads();
  if (tid == 0) {
    const float tot = red[0] + red[1] + red[2] + red[3];
    lp[b] = -0.5f * tot / (float)cKL + (-0.5f * kLOG2PI + S);
  }
}

__global__ void lpmean_kernel(const float* __restrict__ lp, float* __restrict__ outm) {
  __shared__ float red[128];
  const int tid = threadIdx.x;
  red[tid] = lp[tid];
  __syncthreads();
  for (int off = 64; off > 0; off >>= 1) {
    if (tid < off) red[tid] += red[tid + off];
    __syncthreads();
  }
  if (tid == 0) outm[0] = red[0] / 128.0f;
}

extern "C" void kernel_launch(void* const* d_in, const int* in_sizes, int n_in,
                              void* d_out, int out_size, void* d_ws, size_t ws_size,
                              hipStream_t stream) {
  const float* x    = (const float*)d_in[0];
  const float* Wq   = (const float*)d_in[1];
  const float* bq   = (const float*)d_in[2];
  const float* Wk   = (const float*)d_in[3];
  const float* bk   = (const float*)d_in[4];
  const float* Wih  = (const float*)d_in[5];
  const float* Whh  = (const float*)d_in[6];
  const float* bih  = (const float*)d_in[7];
  const float* bhh  = (const float*)d_in[8];
  const float* gWn  = (const float*)d_in[9];
  const float* gbn  = (const float*)d_in[10];
  const float* gWr  = (const float*)d_in[11];
  const float* gW2  = (const float*)d_in[12];
  const float* gb2  = (const float*)d_in[13];
  const float* W1   = (const float*)d_in[14];
  const float* b1   = (const float*)d_in[15];
  const float* bn1g = (const float*)d_in[16];
  const float* bn1b = (const float*)d_in[17];
  const float* bn1m = (const float*)d_in[18];
  const float* bn1v = (const float*)d_in[19];
  const float* W2m  = (const float*)d_in[20];
  const float* b2m  = (const float*)d_in[21];
  const float* bn2g = (const float*)d_in[22];
  const float* bn2b = (const float*)d_in[23];
  const float* bn2m = (const float*)d_in[24];
  const float* bn2v = (const float*)d_in[25];
  const float* W3   = (const float*)d_in[26];
  const float* b3   = (const float*)d_in[27];
  const float* annW = (const float*)d_in[28];
  const float* annb = (const float*)d_in[29];
  const float* abg  = (const float*)d_in[30];
  const float* abb  = (const float*)d_in[31];
  const float* abm  = (const float*)d_in[32];
  const float* abv  = (const float*)d_in[33];
  const float* mob  = (const float*)d_in[38];
  const float* mlg  = (const float*)d_in[39];
  const float* mbeta= (const float*)d_in[40];

  float* ws = (float*)d_ws;
  float* qb    = ws;                    // 391680
  float* kb    = ws + 391680;           // 391680
  float* graph = ws + 783360;           // 332928
  float* hbuf  = ws + 1116288;          // 12533760
  float* z1    = ws + 13650048;         // 64000
  float* z2    = ws + 13714048;         // 64000  (total 13778048 floats = 55.1 MB)
  float* partial = hbuf;                // reuse: h dead after gnn; needs 3.26M floats

  float* outF = (float*)d_out;
  float* hid  = outF;                   // 12800
  float* lpm  = outF + 12800;           // 1
  float* hgcn = outF + 12801;           // 12533760
  float* lp   = outF + 12546561;        // 128

  qk_kernel<<<816, 256, 0, stream>>>(x, Wq, bq, Wk, bk, qb, kb);
  attn_kernel<<<128, 256, 0, stream>>>(qb, kb, graph);
  lstm_kernel<<<1632, 256, 0, stream>>>(x, Wih, Whh, bih, bhh, hbuf);
  gnn_kernel<<<dim3(60, 128), 256, 0, stream>>>(hbuf, graph, gWn, gbn, gWr, gW2, gb2, hgcn);
  mlp_kernel<<<63, 256, 0, stream>>>(x, 3060, W1, 500, b1, bn1g, bn1b, bn1m, bn1v, z1);
  mlp_kernel<<<63, 256, 0, stream>>>(z1, 500, W2m, 500, b2m, bn2g, bn2b, bn2m, bn2v, z2);
  w3_kernel<<<1530, 256, 0, stream>>>(z2, W3, b3, hgcn);
  ann_kernel<<<255, 256, 0, stream>>>(hgcn, annW, partial);
  annred_kernel<<<50, 256, 0, stream>>>(partial, annb, abg, abb, abm, abv, hid);
  logp_kernel<<<128, 256, 0, stream>>>(x, mob, mlg, mbeta, lp);
  lpmean_kernel<<<1, 128, 0, stream>>>(lp, lpm);
}

// Round 2
// 1520.026 us; speedup vs baseline: 1.3997x; 1.3997x over previous
//
#include <hip/hip_runtime.h>
#include <math.h>

constexpr int cB = 128;
constexpr int cK = 51;
constexpr int cL = 60;
constexpr int cH = 32;
constexpr int cC = 60;           // L*D
constexpr int cKL = 3060;        // K*L
constexpr int cKL32 = 97920;     // K*L*32
constexpr float kLOG2PI = 1.8378770664093453f;

__device__ __forceinline__ float fsig(float x) { return 1.0f / (1.0f + __expf(-x)); }
__device__ __forceinline__ float ftanh(float x) {
  float e = __expf(2.0f * x);
  return 1.0f - 2.0f / (e + 1.0f);
}

// ---------------- q/k projections: rows = B*K = 6528, 8 rows/block ----------------
__global__ __launch_bounds__(256) void qk_kernel(
    const float* __restrict__ x, const float* __restrict__ Wq, const float* __restrict__ bq,
    const float* __restrict__ Wk, const float* __restrict__ bk,
    float* __restrict__ q, float* __restrict__ kx) {
  __shared__ float xs[8][cC];
  const int row0 = blockIdx.x * 8;
  const int tid = threadIdx.x;
  for (int idx = tid; idx < 8 * cC; idx += 256) {
    int lr = idx / cC, t = idx % cC;
    xs[lr][t] = x[(row0 + lr) * cC + t];
  }
  __syncthreads();
  for (int idx = tid; idx < 8 * 2 * cC; idx += 256) {
    int col = idx % cC;
    int r2 = idx / cC;
    int m = r2 & 1, lr = r2 >> 1;
    const float* W = m ? Wk : Wq;
    float acc = m ? bk[col] : bq[col];
    #pragma unroll 4
    for (int t = 0; t < cC; ++t) acc += xs[lr][t] * W[t * cC + col];
    float* outp = m ? kx : q;
    outp[(row0 + lr) * cC + col] = acc;
  }
}

// ---------------- score = q @ reshape(k) / sqrt(60); softmax over axis=1 ----------------
__global__ __launch_bounds__(256) void attn_kernel(
    const float* __restrict__ q, const float* __restrict__ kx, float* __restrict__ graph) {
  __shared__ float qb[cKL];
  __shared__ float kb[cKL];
  __shared__ float sc[cK * cK];
  __shared__ float cmax[cK], csum[cK];
  const int b = blockIdx.x;
  const int tid = threadIdx.x;
  for (int idx = tid; idx < cKL; idx += 256) {
    qb[idx] = q[b * cKL + idx];
    kb[idx] = kx[b * cKL + idx];
  }
  __syncthreads();
  const float scale = 1.0f / sqrtf(60.0f);
  for (int idx = tid; idx < cK * cK; idx += 256) {
    int i = idx / cK, j = idx % cK;
    float acc = 0.0f;
    #pragma unroll 4
    for (int t = 0; t < cC; ++t) acc += qb[i * cC + t] * kb[t * cK + j];
    sc[idx] = acc * scale;
  }
  __syncthreads();
  if (tid < cK) {
    float m = -1e30f;
    for (int i = 0; i < cK; ++i) m = fmaxf(m, sc[i * cK + tid]);
    float ssum = 0.0f;
    for (int i = 0; i < cK; ++i) ssum += __expf(sc[i * cK + tid] - m);
    cmax[tid] = m; csum[tid] = ssum;
  }
  __syncthreads();
  for (int idx = tid; idx < cK * cK; idx += 256) {
    int j = idx % cK;
    graph[b * cK * cK + idx] = __expf(sc[idx] - cmax[j]) / csum[j];
  }
}

// ---------------- LSTM: one wave (64 lanes) per sequence, 4 sequences/block ----------------
__global__ __launch_bounds__(256) void lstm_kernel(
    const float* __restrict__ x, const float* __restrict__ Wih, const float* __restrict__ Whh,
    const float* __restrict__ bih, const float* __restrict__ bhh, float* __restrict__ hout) {
  const int wave = threadIdx.x >> 6;
  const int lane = threadIdx.x & 63;
  const int seq = blockIdx.x * 4 + wave;   // < 6528
  const int j = lane;
  float w0[32], w1[32];
  #pragma unroll
  for (int k2 = 0; k2 < 32; ++k2) {
    w0[k2] = Whh[j * 32 + k2];
    w1[k2] = Whh[(j + 64) * 32 + k2];
  }
  const float wi0 = Wih[j], wi1 = Wih[j + 64];
  const float bb0 = bih[j] + bhh[j];
  const float bb1 = bih[j + 64] + bhh[j + 64];
  const float xr = (lane < cL) ? x[seq * cL + lane] : 0.0f;
  float h = 0.0f, c = 0.0f;
  float* outp = hout + (size_t)seq * cL * cH;
  for (int t = 0; t < cL; ++t) {
    const float xt = __shfl(xr, t);
    float a0 = bb0 + wi0 * xt;
    float a1 = bb1 + wi1 * xt;
    #pragma unroll
    for (int k2 = 0; k2 < 32; ++k2) {
      const float hk = __shfl(h, k2);
      a0 += w0[k2] * hk;
      a1 += w1[k2] * hk;
    }
    const float sA = fsig(a0);     // lanes<32: sig(i); lanes>=32: sig(f)
    const float sB = fsig(a1);     // lanes>=32: sig(o)
    const float tB = ftanh(a1);    // lanes<32: tanh(g)
    const float p = sA * tB;
    const float sf = __shfl(sA, (lane & 31) + 32);
    const float so = __shfl(sB, (lane & 31) + 32);
    c = sf * c + p;
    h = so * ftanh(c);
    if (lane < 32) outp[t * cH + lane] = h;
  }
}

// ---------------- einsum('bkld,bkj->bjld') + GNN, fused per (b,l) ----------------
__global__ __launch_bounds__(256) void gnn_kernel(
    const float* __restrict__ hbuf, const float* __restrict__ graph,
    const float* __restrict__ Wn, const float* __restrict__ bn_,
    const float* __restrict__ Wr, const float* __restrict__ W2,
    const float* __restrict__ b2, float* __restrict__ out) {
  __shared__ float g[cK * cK];
  __shared__ __align__(16) float hl[cK][cH];
  __shared__ __align__(16) float hm[cK][cH];
  __shared__ __align__(16) float agg[cK][cH];
  __shared__ __align__(16) float rl[cK][cH];
  __shared__ __align__(16) float wn[cH * cH];
  __shared__ __align__(16) float wr[cH * cH];
  __shared__ __align__(16) float w2[cH * cH];
  __shared__ float bnb[cH], b2b[cH];
  const int l = blockIdx.x;
  const int b = blockIdx.y;
  const int tid = threadIdx.x;
  for (int idx = tid; idx < cK * cK; idx += 256) g[idx] = graph[b * cK * cK + idx];
  for (int idx = tid; idx < cH * cH; idx += 256) { wn[idx] = Wn[idx]; wr[idx] = Wr[idx]; w2[idx] = W2[idx]; }
  if (tid < cH) { bnb[tid] = bn_[tid]; b2b[tid] = b2[tid]; }
  const float* hb = hbuf + (size_t)b * cK * cL * cH;
  for (int idx = tid; idx < cK * cH; idx += 256) {
    int kk = idx >> 5, d = idx & 31;
    hl[kk][d] = hb[(kk * cL + l) * cH + d];
    hm[kk][d] = (l > 0) ? hb[(kk * cL + (l - 1)) * cH + d] : 0.0f;
  }
  __syncthreads();
  const int jp = tid >> 3;
  const int dq = tid & 7;
  const int j0 = jp * 2, d0 = dq * 4;
  const bool act = (jp < 26);
  const bool has1 = (j0 + 1 < cK);
  if (act) {
    float a0[4] = {0, 0, 0, 0}, a1[4] = {0, 0, 0, 0};
    for (int kk = 0; kk < cK; ++kk) {
      const float g0 = g[kk * cK + j0];
      const float g1 = has1 ? g[kk * cK + j0 + 1] : 0.0f;
      const float4 hv = *reinterpret_cast<const float4*>(&hl[kk][d0]);
      a0[0] += g0 * hv.x; a0[1] += g0 * hv.y; a0[2] += g0 * hv.z; a0[3] += g0 * hv.w;
      a1[0] += g1 * hv.x; a1[1] += g1 * hv.y; a1[2] += g1 * hv.z; a1[3] += g1 * hv.w;
    }
    #pragma unroll
    for (int dd = 0; dd < 4; ++dd) {
      agg[j0][d0 + dd] = a0[dd];
      if (has1) agg[j0 + 1][d0 + dd] = a1[dd];
    }
  }
  __syncthreads();
  if (act) {
    float r0v[4], r1v[4];
    #pragma unroll
    for (int dd = 0; dd < 4; ++dd) { r0v[dd] = bnb[d0 + dd]; r1v[dd] = bnb[d0 + dd]; }
    for (int e = 0; e < cH; ++e) {
      const float ag0 = agg[j0][e], hh0 = hm[j0][e];
      const float ag1 = has1 ? agg[j0 + 1][e] : 0.0f;
      const float hh1 = has1 ? hm[j0 + 1][e] : 0.0f;
      const float4 wnv = *reinterpret_cast<const float4*>(&wn[e * cH + d0]);
      const float4 wrv = *reinterpret_cast<const float4*>(&wr[e * cH + d0]);
      r0v[0] += ag0 * wnv.x + hh0 * wrv.x; r0v[1] += ag0 * wnv.y + hh0 * wrv.y;
      r0v[2] += ag0 * wnv.z + hh0 * wrv.z; r0v[3] += ag0 * wnv.w + hh0 * wrv.w;
      r1v[0] += ag1 * wnv.x + hh1 * wrv.x; r1v[1] += ag1 * wnv.y + hh1 * wrv.y;
      r1v[2] += ag1 * wnv.z + hh1 * wrv.z; r1v[3] += ag1 * wnv.w + hh1 * wrv.w;
    }
    #pragma unroll
    for (int dd = 0; dd < 4; ++dd) {
      rl[j0][d0 + dd] = fmaxf(r0v[dd], 0.0f);
      if (has1) rl[j0 + 1][d0 + dd] = fmaxf(r1v[dd], 0.0f);
    }
  }
  __syncthreads();
  if (act) {
    float o0[4], o1[4];
    #pragma unroll
    for (int dd = 0; dd < 4; ++dd) { o0[dd] = b2b[d0 + dd]; o1[dd] = b2b[d0 + dd]; }
    for (int e = 0; e < cH; ++e) {
      const float rr0 = rl[j0][e];
      const float rr1 = has1 ? rl[j0 + 1][e] : 0.0f;
      const float4 w2v = *reinterpret_cast<const float4*>(&w2[e * cH + d0]);
      o0[0] += rr0 * w2v.x; o0[1] += rr0 * w2v.y; o0[2] += rr0 * w2v.z; o0[3] += rr0 * w2v.w;
      o1[0] += rr1 * w2v.x; o1[1] += rr1 * w2v.y; o1[2] += rr1 * w2v.z; o1[3] += rr1 * w2v.w;
    }
    size_t base0 = (((size_t)b * cK + j0) * cL + l) * cH + d0;
    #pragma unroll
    for (int dd = 0; dd < 4; ++dd) out[base0 + dd] = o0[dd];
    if (has1) {
      size_t base1 = (((size_t)b * cK + j0 + 1) * cL + l) * cH + d0;
      #pragma unroll
      for (int dd = 0; dd < 4; ++dd) out[base1 + dd] = o1[dd];
    }
  }
}

// ---------------- split-K GEMM: partial[s] = A[:, ks:ks+64] @ W[ks:ks+64, n0:n0+64] ----------------
// A: 128 x K, W: K x N. Grid: (ceil(N/64), S). Single LDS shot, no K-loop.
__global__ __launch_bounds__(256) void gemm_splitk_kernel(
    const float* __restrict__ A, const float* __restrict__ W,
    int K, int N, float* __restrict__ partial) {
  __shared__ __align__(16) float At[128][65];
  __shared__ __align__(16) float Wt[64][64];
  const int tid = threadIdx.x;
  const int n0 = blockIdx.x * 64;
  const int k0 = blockIdx.y * 64;
  const int kw = min(64, K - k0);
  for (int idx = tid; idx < 128 * 64; idx += 256) {
    int r = idx >> 6, kk = idx & 63;
    At[r][kk] = (kk < kw) ? A[(size_t)r * K + k0 + kk] : 0.0f;
  }
  for (int idx = tid; idx < 64 * 64; idx += 256) {
    int kk = idx >> 6, cc = idx & 63;
    Wt[kk][cc] = (kk < kw && n0 + cc < N) ? W[(size_t)(k0 + kk) * N + n0 + cc] : 0.0f;
  }
  __syncthreads();
  const int cg = tid & 15, rg = tid >> 4;
  const int c0 = cg * 4, r0 = rg * 8;
  float acc[8][4];
  #pragma unroll
  for (int i = 0; i < 8; ++i)
    #pragma unroll
    for (int jj = 0; jj < 4; ++jj) acc[i][jj] = 0.0f;
  for (int kk = 0; kk < 64; kk += 2) {
    const float4 wv0 = *reinterpret_cast<const float4*>(&Wt[kk][c0]);
    const float4 wv1 = *reinterpret_cast<const float4*>(&Wt[kk + 1][c0]);
    #pragma unroll
    for (int i = 0; i < 8; ++i) {
      const float2 av = *reinterpret_cast<const float2*>(&At[r0 + i][kk]);
      acc[i][0] += av.x * wv0.x + av.y * wv1.x;
      acc[i][1] += av.x * wv0.y + av.y * wv1.y;
      acc[i][2] += av.x * wv0.z + av.y * wv1.z;
      acc[i][3] += av.x * wv0.w + av.y * wv1.w;
    }
  }
  float* p = partial + (size_t)blockIdx.y * 128 * N;
  #pragma unroll
  for (int i = 0; i < 8; ++i) {
    #pragma unroll
    for (int jj = 0; jj < 4; ++jj) {
      const int cc = n0 + c0 + jj;
      if (cc < N) p[(r0 + i) * N + cc] = acc[i][jj];
    }
  }
}

// ---------------- reduce split-K partials + bias + relu + bn ----------------
__global__ __launch_bounds__(256) void mlpred_kernel(
    const float* __restrict__ partial, int S, int N,
    const float* __restrict__ bias, const float* __restrict__ gg,
    const float* __restrict__ bb, const float* __restrict__ mm,
    const float* __restrict__ vv, float* __restrict__ outz) {
  const int oi = blockIdx.x * 256 + threadIdx.x;
  if (oi >= 128 * N) return;
  float s = 0.0f;
  for (int p = 0; p < S; ++p) s += partial[(size_t)p * 128 * N + oi];
  const int c = oi % N;
  const float z = fmaxf(s + bias[c], 0.0f);
  outz[oi] = (z - mm[c]) * rsqrtf(vv[c] + 1e-5f) * gg[c] + bb[c];
}

// ---------------- big GEMM: d_out.h_gcn = z2 @ W3 + b3 + h_gcn_pre (RMW) ----------------
__global__ __launch_bounds__(256) void w3_kernel(
    const float* __restrict__ z2, const float* __restrict__ W3,
    const float* __restrict__ b3, float* __restrict__ outh) {
  __shared__ __align__(16) float At[128][52];
  __shared__ __align__(16) float Wt[50][64];
  const int tid = threadIdx.x;
  const int n0 = blockIdx.x * 64;
  const int cg = tid & 15, rg = tid >> 4;
  const int c0 = cg * 4, r0 = rg * 8;
  float acc[8][4];
  #pragma unroll
  for (int i = 0; i < 8; ++i)
    #pragma unroll
    for (int jj = 0; jj < 4; ++jj) acc[i][jj] = 0.0f;
  for (int k0 = 0; k0 < 500; k0 += 50) {
    for (int idx = tid; idx < 128 * 50; idx += 256) {
      int r = idx / 50, kk = idx % 50;
      At[r][kk] = z2[r * 500 + k0 + kk];
    }
    for (int idx = tid; idx < 50 * 64; idx += 256) {
      int kk = idx >> 6, cc2 = idx & 63;
      Wt[kk][cc2] = W3[(size_t)(k0 + kk) * cKL32 + n0 + cc2];
    }
    __syncthreads();
    for (int kk = 0; kk < 50; kk += 2) {
      const float4 wv0 = *reinterpret_cast<const float4*>(&Wt[kk][c0]);
      const float4 wv1 = *reinterpret_cast<const float4*>(&Wt[kk + 1][c0]);
      #pragma unroll
      for (int i = 0; i < 8; ++i) {
        const float2 av = *reinterpret_cast<const float2*>(&At[r0 + i][kk]);
        acc[i][0] += av.x * wv0.x + av.y * wv1.x;
        acc[i][1] += av.x * wv0.y + av.y * wv1.y;
        acc[i][2] += av.x * wv0.z + av.y * wv1.z;
        acc[i][3] += av.x * wv0.w + av.y * wv1.w;
      }
    }
    __syncthreads();
  }
  #pragma unroll
  for (int i = 0; i < 8; ++i) {
    const int r = r0 + i;
    const size_t base = (size_t)r * cKL32 + n0 + c0;
    #pragma unroll
    for (int jj = 0; jj < 4; ++jj) {
      const int n = n0 + c0 + jj;
      outh[base + jj] = acc[i][jj] + b3[n] + outh[base + jj];
    }
  }
}

// ---------------- ann GEMM split-K ----------------
__global__ __launch_bounds__(256) void ann_kernel(
    const float* __restrict__ hg, const float* __restrict__ annW, float* __restrict__ partial) {
  __shared__ __align__(16) float At[128][34];
  __shared__ __align__(16) float Wt[32][128];
  const int tid = threadIdx.x;
  const int bx = blockIdx.x;   // 255
  const int k0 = bx * 384;
  const int cg = tid & 15, rg = tid >> 4;
  const int c0 = cg * 8, r0 = rg * 8;
  float acc[8][8];
  #pragma unroll
  for (int i = 0; i < 8; ++i)
    #pragma unroll
    for (int jj = 0; jj < 8; ++jj) acc[i][jj] = 0.0f;
  for (int st = 0; st < 12; ++st) {
    const int kb = k0 + st * 32;
    for (int idx = tid; idx < 128 * 32; idx += 256) {
      int r = idx >> 5, kk = idx & 31;
      At[r][kk] = hg[(size_t)r * cKL32 + kb + kk];
    }
    for (int idx = tid; idx < 32 * 128; idx += 256) {
      int kk = idx >> 7, cc2 = idx & 127;
      Wt[kk][cc2] = (cc2 < 100) ? annW[(size_t)(kb + kk) * 100 + cc2] : 0.0f;
    }
    __syncthreads();
    for (int kk = 0; kk < 32; kk += 2) {
      const float4 w00 = *reinterpret_cast<const float4*>(&Wt[kk][c0]);
      const float4 w01 = *reinterpret_cast<const float4*>(&Wt[kk][c0 + 4]);
      const float4 w10 = *reinterpret_cast<const float4*>(&Wt[kk + 1][c0]);
      const float4 w11 = *reinterpret_cast<const float4*>(&Wt[kk + 1][c0 + 4]);
      #pragma unroll
      for (int i = 0; i < 8; ++i) {
        const float2 av = *reinterpret_cast<const float2*>(&At[r0 + i][kk]);
        acc[i][0] += av.x * w00.x + av.y * w10.x;
        acc[i][1] += av.x * w00.y + av.y * w10.y;
        acc[i][2] += av.x * w00.z + av.y * w10.z;
        acc[i][3] += av.x * w00.w + av.y * w10.w;
        acc[i][4] += av.x * w01.x + av.y * w11.x;
        acc[i][5] += av.x * w01.y + av.y * w11.y;
        acc[i][6] += av.x * w01.z + av.y * w11.z;
        acc[i][7] += av.x * w01.w + av.y * w11.w;
      }
    }
    __syncthreads();
  }
  #pragma unroll
  for (int i = 0; i < 8; ++i) {
    #pragma unroll
    for (int jj = 0; jj < 8; ++jj) {
      const int cc = c0 + jj;
      if (cc < 100) partial[(size_t)bx * 12800 + (r0 + i) * 100 + cc] = acc[i][jj];
    }
  }
}

__global__ __launch_bounds__(256) void annred_kernel(
    const float* __restrict__ partial, const float* __restrict__ ab,
    const float* __restrict__ gg, const float* __restrict__ bb,
    const float* __restrict__ mm, const float* __restrict__ vv, float* __restrict__ hid) {
  const int oi = blockIdx.x * 256 + threadIdx.x;   // < 12800
  if (oi < 12800) {
    float s = 0.0f;
    for (int p = 0; p < 255; ++p) s += partial[(size_t)p * 12800 + oi];
    const int c = oi % 100;
    const float z = fmaxf(s + ab[c], 0.0f);
    hid[oi] = (z - mm[c]) * rsqrtf(vv[c] + 1e-5f) * gg[c] + bb[c];
  }
}

// ---------------- log_prob: MAF collapses to u = a*x + b (mask_out all zeros) ----------------
__global__ __launch_bounds__(256) void logp_kernel(
    const float* __restrict__ x, const float* __restrict__ mob,
    const float* __restrict__ mlg, const float* __restrict__ mbeta, float* __restrict__ lp) {
  const int b = blockIdx.x;
  const int tid = threadIdx.x;
  const float rs = rsqrtf(1.0f + 1e-5f);
  const float A0 = __expf(mlg[0] - mob[1]) * rs;
  const float B0 = -mob[0] * __expf(-mob[1]) * __expf(mlg[0]) * rs + mbeta[0];
  const float A1 = __expf(mlg[1] - mob[3]) * rs;
  const float B1 = -mob[2] * __expf(-mob[3]) * __expf(mlg[1]) * rs + mbeta[1];
  const float S = (mlg[0] - mob[1]) + (mlg[1] - mob[3]) - logf(1.0f + 1e-5f);
  const float a = A1 * A0;
  const float bc = A1 * B0 + B1;
  float s = 0.0f;
  for (int t = tid; t < cKL; t += 256) {
    const float u = a * x[b * cKL + t] + bc;
    s += u * u;
  }
  #pragma unroll
  for (int off = 32; off > 0; off >>= 1) s += __shfl_down(s, off);
  __shared__ float red[4];
  if ((tid & 63) == 0) red[tid >> 6] = s;
  __syncthreads();
  if (tid == 0) {
    const float tot = red[0] + red[1] + red[2] + red[3];
    lp[b] = -0.5f * tot / (float)cKL + (-0.5f * kLOG2PI + S);
  }
}

__global__ void lpmean_kernel(const float* __restrict__ lp, float* __restrict__ outm) {
  __shared__ float red[128];
  const int tid = threadIdx.x;
  red[tid] = lp[tid];
  __syncthreads();
  for (int off = 64; off > 0; off >>= 1) {
    if (tid < off) red[tid] += red[tid + off];
    __syncthreads();
  }
  if (tid == 0) outm[0] = red[0] / 128.0f;
}

extern "C" void kernel_launch(void* const* d_in, const int* in_sizes, int n_in,
                              void* d_out, int out_size, void* d_ws, size_t ws_size,
                              hipStream_t stream) {
  const float* x    = (const float*)d_in[0];
  const float* Wq   = (const float*)d_in[1];
  const float* bq   = (const float*)d_in[2];
  const float* Wk   = (const float*)d_in[3];
  const float* bk   = (const float*)d_in[4];
  const float* Wih  = (const float*)d_in[5];
  const float* Whh  = (const float*)d_in[6];
  const float* bih  = (const float*)d_in[7];
  const float* bhh  = (const float*)d_in[8];
  const float* gWn  = (const float*)d_in[9];
  const float* gbn  = (const float*)d_in[10];
  const float* gWr  = (const float*)d_in[11];
  const float* gW2  = (const float*)d_in[12];
  const float* gb2  = (const float*)d_in[13];
  const float* W1   = (const float*)d_in[14];
  const float* b1   = (const float*)d_in[15];
  const float* bn1g = (const float*)d_in[16];
  const float* bn1b = (const float*)d_in[17];
  const float* bn1m = (const float*)d_in[18];
  const float* bn1v = (const float*)d_in[19];
  const float* W2m  = (const float*)d_in[20];
  const float* b2m  = (const float*)d_in[21];
  const float* bn2g = (const float*)d_in[22];
  const float* bn2b = (const float*)d_in[23];
  const float* bn2m = (const float*)d_in[24];
  const float* bn2v = (const float*)d_in[25];
  const float* W3   = (const float*)d_in[26];
  const float* b3   = (const float*)d_in[27];
  const float* annW = (const float*)d_in[28];
  const float* annb = (const float*)d_in[29];
  const float* abg  = (const float*)d_in[30];
  const float* abb  = (const float*)d_in[31];
  const float* abm  = (const float*)d_in[32];
  const float* abv  = (const float*)d_in[33];
  const float* mob  = (const float*)d_in[38];
  const float* mlg  = (const float*)d_in[39];
  const float* mbeta= (const float*)d_in[40];

  float* ws = (float*)d_ws;
  float* qb    = ws;                    // 391680
  float* kb    = ws + 391680;           // 391680
  float* graph = ws + 783360;           // 332928
  float* hbuf  = ws + 1116288;          // 12533760
  float* z1    = ws + 13650048;         // 64000
  float* z2    = ws + 13714048;         // 64000  (total 13778048 floats = 55.1 MB)
  float* partial = hbuf;                // ann split-K partials: 255*12800 = 3.264M floats
  float* mp    = hbuf + 4000000;        // mlp split-K partials: up to 48*64000 = 3.072M floats
                                        // (hbuf dead between gnn and ann; both fit disjointly)

  float* outF = (float*)d_out;
  float* hid  = outF;                   // 12800
  float* lpm  = outF + 12800;           // 1
  float* hgcn = outF + 12801;           // 12533760
  float* lp   = outF + 12546561;        // 128

  qk_kernel<<<816, 256, 0, stream>>>(x, Wq, bq, Wk, bk, qb, kb);
  attn_kernel<<<128, 256, 0, stream>>>(qb, kb, graph);
  lstm_kernel<<<1632, 256, 0, stream>>>(x, Wih, Whh, bih, bhh, hbuf);
  gnn_kernel<<<dim3(60, 128), 256, 0, stream>>>(hbuf, graph, gWn, gbn, gWr, gW2, gb2, hgcn);
  // mlp1: K=3060 -> 48 splits of 64; mlp2: K=500 -> 8 splits
  gemm_splitk_kernel<<<dim3(8, 48), 256, 0, stream>>>(x, W1, 3060, 500, mp);
  mlpred_kernel<<<250, 256, 0, stream>>>(mp, 48, 500, b1, bn1g, bn1b, bn1m, bn1v, z1);
  gemm_splitk_kernel<<<dim3(8, 8), 256, 0, stream>>>(z1, W2m, 500, 500, mp);
  mlpred_kernel<<<250, 256, 0, stream>>>(mp, 8, 500, b2m, bn2g, bn2b, bn2m, bn2v, z2);
  w3_kernel<<<1530, 256, 0, stream>>>(z2, W3, b3, hgcn);
  ann_kernel<<<255, 256, 0, stream>>>(hgcn, annW, partial);
  annred_kernel<<<50, 256, 0, stream>>>(partial, annb, abg, abb, abm, abv, hid);
  logp_kernel<<<128, 256, 0, stream>>>(x, mob, mlg, mbeta, lp);
  lpmean_kernel<<<1, 128, 0, stream>>>(lp, lpm);
}

// Round 3
// 1195.986 us; speedup vs baseline: 1.7789x; 1.2709x over previous
//
#include <hip/hip_runtime.h>
#include <math.h>

constexpr int cB = 128;
constexpr int cK = 51;
constexpr int cL = 60;
constexpr int cH = 32;
constexpr int cC = 60;           // L*D
constexpr int cKL = 3060;        // K*L
constexpr int cKL32 = 97920;     // K*L*32
constexpr float kLOG2PI = 1.8378770664093453f;

__device__ __forceinline__ float fsig(float x) { return 1.0f / (1.0f + __expf(-x)); }
__device__ __forceinline__ float ftanh(float x) {
  float e = __expf(2.0f * x);
  return 1.0f - 2.0f / (e + 1.0f);
}

// ---------------- q/k projections: rows = B*K = 6528, 8 rows/block ----------------
__global__ __launch_bounds__(256) void qk_kernel(
    const float* __restrict__ x, const float* __restrict__ Wq, const float* __restrict__ bq,
    const float* __restrict__ Wk, const float* __restrict__ bk,
    float* __restrict__ q, float* __restrict__ kx) {
  __shared__ float xs[8][cC];
  const int row0 = blockIdx.x * 8;
  const int tid = threadIdx.x;
  for (int idx = tid; idx < 8 * cC; idx += 256) {
    int lr = idx / cC, t = idx % cC;
    xs[lr][t] = x[(row0 + lr) * cC + t];
  }
  __syncthreads();
  for (int idx = tid; idx < 8 * 2 * cC; idx += 256) {
    int col = idx % cC;
    int r2 = idx / cC;
    int m = r2 & 1, lr = r2 >> 1;
    const float* W = m ? Wk : Wq;
    float acc = m ? bk[col] : bq[col];
    #pragma unroll 4
    for (int t = 0; t < cC; ++t) acc += xs[lr][t] * W[t * cC + col];
    float* outp = m ? kx : q;
    outp[(row0 + lr) * cC + col] = acc;
  }
}

// ---------------- score = q @ reshape(k) / sqrt(60); softmax over axis=1 ----------------
__global__ __launch_bounds__(256) void attn_kernel(
    const float* __restrict__ q, const float* __restrict__ kx, float* __restrict__ graph) {
  __shared__ float qb[cKL];
  __shared__ float kb[cKL];
  __shared__ float sc[cK * cK];
  __shared__ float cmax[cK], csum[cK];
  const int b = blockIdx.x;
  const int tid = threadIdx.x;
  for (int idx = tid; idx < cKL; idx += 256) {
    qb[idx] = q[b * cKL + idx];
    kb[idx] = kx[b * cKL + idx];
  }
  __syncthreads();
  const float scale = 1.0f / sqrtf(60.0f);
  for (int idx = tid; idx < cK * cK; idx += 256) {
    int i = idx / cK, j = idx % cK;
    float acc = 0.0f;
    #pragma unroll 4
    for (int t = 0; t < cC; ++t) acc += qb[i * cC + t] * kb[t * cK + j];
    sc[idx] = acc * scale;
  }
  __syncthreads();
  if (tid < cK) {
    float m = -1e30f;
    for (int i = 0; i < cK; ++i) m = fmaxf(m, sc[i * cK + tid]);
    float ssum = 0.0f;
    for (int i = 0; i < cK; ++i) ssum += __expf(sc[i * cK + tid] - m);
    cmax[tid] = m; csum[tid] = ssum;
  }
  __syncthreads();
  for (int idx = tid; idx < cK * cK; idx += 256) {
    int j = idx % cK;
    graph[b * cK * cK + idx] = __expf(sc[idx] - cmax[j]) / csum[j];
  }
}

// ---------------- LSTM: one wave (64 lanes) per sequence, 4 sequences/block ----------------
__global__ __launch_bounds__(256) void lstm_kernel(
    const float* __restrict__ x, const float* __restrict__ Wih, const float* __restrict__ Whh,
    const float* __restrict__ bih, const float* __restrict__ bhh, float* __restrict__ hout) {
  const int wave = threadIdx.x >> 6;
  const int lane = threadIdx.x & 63;
  const int seq = blockIdx.x * 4 + wave;   // < 6528
  const int j = lane;
  float w0[32], w1[32];
  #pragma unroll
  for (int k2 = 0; k2 < 32; ++k2) {
    w0[k2] = Whh[j * 32 + k2];
    w1[k2] = Whh[(j + 64) * 32 + k2];
  }
  const float wi0 = Wih[j], wi1 = Wih[j + 64];
  const float bb0 = bih[j] + bhh[j];
  const float bb1 = bih[j + 64] + bhh[j + 64];
  const float xr = (lane < cL) ? x[seq * cL + lane] : 0.0f;
  float h = 0.0f, c = 0.0f;
  float* outp = hout + (size_t)seq * cL * cH;
  for (int t = 0; t < cL; ++t) {
    const float xt = __shfl(xr, t);
    float a0 = bb0 + wi0 * xt;
    float a1 = bb1 + wi1 * xt;
    #pragma unroll
    for (int k2 = 0; k2 < 32; ++k2) {
      const float hk = __shfl(h, k2);
      a0 += w0[k2] * hk;
      a1 += w1[k2] * hk;
    }
    const float sA = fsig(a0);
    const float sB = fsig(a1);
    const float tB = ftanh(a1);
    const float p = sA * tB;
    const float sf = __shfl(sA, (lane & 31) + 32);
    const float so = __shfl(sB, (lane & 31) + 32);
    c = sf * c + p;
    h = so * ftanh(c);
    if (lane < 32) outp[t * cH + lane] = h;
  }
}

// ---------------- agg: per b, agg = G^T (51x51) @ H (51x1920), 128-col tiles ----------------
// writes h_gcn region of d_out (scalar stores: d_out+12801 is not 16B aligned)
__global__ __launch_bounds__(256) void agg_kernel(
    const float* __restrict__ hbuf, const float* __restrict__ graph,
    float* __restrict__ aggout) {
  __shared__ float G[cK * cK];                 // 2601 floats
  __shared__ __align__(16) float Ht[cK][128];  // 51 x 128
  const int b = blockIdx.y;
  const int c0 = blockIdx.x * 128;
  const int tid = threadIdx.x;
  for (int idx = tid; idx < cK * cK; idx += 256) G[idx] = graph[b * cK * cK + idx];
  for (int idx = tid; idx < cK * 128; idx += 256) {
    int k = idx >> 7, c = idx & 127;
    Ht[k][c] = hbuf[((size_t)b * cK + k) * 1920 + c0 + c];
  }
  __syncthreads();
  const int jg = tid >> 5;      // 0..7
  const int cg = tid & 31;
  const int cc = cg * 4;
  float4 acc[7];
  #pragma unroll
  for (int jj = 0; jj < 7; ++jj) acc[jj] = make_float4(0.f, 0.f, 0.f, 0.f);
  for (int k = 0; k < cK; ++k) {
    const float4 hv = *reinterpret_cast<const float4*>(&Ht[k][cc]);
    #pragma unroll
    for (int jj = 0; jj < 7; ++jj) {
      const int j = jg + jj * 8;
      const float g = (j < cK) ? G[k * cK + j] : 0.0f;
      acc[jj].x += g * hv.x; acc[jj].y += g * hv.y;
      acc[jj].z += g * hv.z; acc[jj].w += g * hv.w;
    }
  }
  #pragma unroll
  for (int jj = 0; jj < 7; ++jj) {
    const int j = jg + jj * 8;
    if (j < cK) {
      const size_t o = ((size_t)b * cK + j) * 1920 + c0 + cc;
      aggout[o + 0] = acc[jj].x; aggout[o + 1] = acc[jj].y;
      aggout[o + 2] = acc[jj].z; aggout[o + 3] = acc[jj].w;
    }
  }
}

// ---------------- gnn2: per-row h_gcn_pre = relu(agg@Wn + bn + hm@Wr) @ W2 + b2 ----------------
// 192 rows/block, in-place on the h_gcn region (row r depends only on agg row r, hbuf row r-1)
__global__ __launch_bounds__(256) void gnn2_kernel(
    const float* __restrict__ hbuf, const float* __restrict__ Wn,
    const float* __restrict__ bn_, const float* __restrict__ Wr,
    const float* __restrict__ W2, const float* __restrict__ b2,
    float* __restrict__ hg) {
  __shared__ __align__(16) float wn[cH * cH];
  __shared__ __align__(16) float wr[cH * cH];
  __shared__ __align__(16) float w2[cH * cH];
  __shared__ float bnb[cH], b2b[cH];
  __shared__ float A_[192][33];   // agg rows, then t1, then never again
  __shared__ float M_[192][33];   // hm rows, then result
  const int tid = threadIdx.x;
  const int row0 = blockIdx.x * 192;
  for (int idx = tid; idx < cH * cH; idx += 256) { wn[idx] = Wn[idx]; wr[idx] = Wr[idx]; w2[idx] = W2[idx]; }
  if (tid < cH) { bnb[tid] = bn_[tid]; b2b[tid] = b2[tid]; }
  for (int idx = tid; idx < 192 * 32; idx += 256) {
    const int r = idx >> 5, d = idx & 31;
    A_[r][d] = hg[(size_t)(row0 + r) * 32 + d];
    const int g = row0 + r;
    const int l = g % 60;
    M_[r][d] = (l > 0) ? hbuf[(size_t)(g - 1) * 32 + d] : 0.0f;
  }
  __syncthreads();
  const int rg = tid >> 2;        // 0..63, rows rg*3..rg*3+2
  const int cg = tid & 3;
  const int c0 = cg * 8;
  const int r0 = rg * 3;
  float acc[3][8];
  #pragma unroll
  for (int i = 0; i < 3; ++i)
    #pragma unroll
    for (int d = 0; d < 8; ++d) acc[i][d] = bnb[c0 + d];
  for (int e = 0; e < cH; ++e) {
    const float4 wn0 = *reinterpret_cast<const float4*>(&wn[e * cH + c0]);
    const float4 wn1 = *reinterpret_cast<const float4*>(&wn[e * cH + c0 + 4]);
    const float4 wr0 = *reinterpret_cast<const float4*>(&wr[e * cH + c0]);
    const float4 wr1 = *reinterpret_cast<const float4*>(&wr[e * cH + c0 + 4]);
    #pragma unroll
    for (int i = 0; i < 3; ++i) {
      const float a = A_[r0 + i][e];
      const float m = M_[r0 + i][e];
      acc[i][0] += a * wn0.x + m * wr0.x; acc[i][1] += a * wn0.y + m * wr0.y;
      acc[i][2] += a * wn0.z + m * wr0.z; acc[i][3] += a * wn0.w + m * wr0.w;
      acc[i][4] += a * wn1.x + m * wr1.x; acc[i][5] += a * wn1.y + m * wr1.y;
      acc[i][6] += a * wn1.z + m * wr1.z; acc[i][7] += a * wn1.w + m * wr1.w;
    }
  }
  __syncthreads();                       // all phase-1 reads done
  #pragma unroll
  for (int i = 0; i < 3; ++i)
    #pragma unroll
    for (int d = 0; d < 8; ++d) A_[r0 + i][c0 + d] = fmaxf(acc[i][d], 0.0f);
  __syncthreads();
  float acc2[3][8];
  #pragma unroll
  for (int i = 0; i < 3; ++i)
    #pragma unroll
    for (int d = 0; d < 8; ++d) acc2[i][d] = b2b[c0 + d];
  for (int e = 0; e < cH; ++e) {
    const float4 w20 = *reinterpret_cast<const float4*>(&w2[e * cH + c0]);
    const float4 w21 = *reinterpret_cast<const float4*>(&w2[e * cH + c0 + 4]);
    #pragma unroll
    for (int i = 0; i < 3; ++i) {
      const float t = A_[r0 + i][e];
      acc2[i][0] += t * w20.x; acc2[i][1] += t * w20.y;
      acc2[i][2] += t * w20.z; acc2[i][3] += t * w20.w;
      acc2[i][4] += t * w21.x; acc2[i][5] += t * w21.y;
      acc2[i][6] += t * w21.z; acc2[i][7] += t * w21.w;
    }
  }
  #pragma unroll
  for (int i = 0; i < 3; ++i)
    #pragma unroll
    for (int d = 0; d < 8; ++d) M_[r0 + i][c0 + d] = acc2[i][d];
  __syncthreads();
  for (int idx = tid; idx < 192 * 32; idx += 256) {
    const int r = idx >> 5, d = idx & 31;
    hg[(size_t)row0 * 32 + idx] = M_[r][d];
  }
}

// ---------------- split-K GEMM: partial[s] = A[:, ks:ks+64] @ W[ks:ks+64, n0:n0+64] ----------------
__global__ __launch_bounds__(256) void gemm_splitk_kernel(
    const float* __restrict__ A, const float* __restrict__ W,
    int K, int N, float* __restrict__ partial) {
  __shared__ __align__(16) float At[128][65];
  __shared__ __align__(16) float Wt[64][64];
  const int tid = threadIdx.x;
  const int n0 = blockIdx.x * 64;
  const int k0 = blockIdx.y * 64;
  const int kw = min(64, K - k0);
  for (int idx = tid; idx < 128 * 64; idx += 256) {
    int r = idx >> 6, kk = idx & 63;
    At[r][kk] = (kk < kw) ? A[(size_t)r * K + k0 + kk] : 0.0f;
  }
  for (int idx = tid; idx < 64 * 64; idx += 256) {
    int kk = idx >> 6, cc = idx & 63;
    Wt[kk][cc] = (kk < kw && n0 + cc < N) ? W[(size_t)(k0 + kk) * N + n0 + cc] : 0.0f;
  }
  __syncthreads();
  const int cg = tid & 15, rg = tid >> 4;
  const int c0 = cg * 4, r0 = rg * 8;
  float acc[8][4];
  #pragma unroll
  for (int i = 0; i < 8; ++i)
    #pragma unroll
    for (int jj = 0; jj < 4; ++jj) acc[i][jj] = 0.0f;
  for (int kk = 0; kk < 64; kk += 2) {
    const float4 wv0 = *reinterpret_cast<const float4*>(&Wt[kk][c0]);
    const float4 wv1 = *reinterpret_cast<const float4*>(&Wt[kk + 1][c0]);
    #pragma unroll
    for (int i = 0; i < 8; ++i) {
      const float2 av = *reinterpret_cast<const float2*>(&At[r0 + i][kk]);
      acc[i][0] += av.x * wv0.x + av.y * wv1.x;
      acc[i][1] += av.x * wv0.y + av.y * wv1.y;
      acc[i][2] += av.x * wv0.z + av.y * wv1.z;
      acc[i][3] += av.x * wv0.w + av.y * wv1.w;
    }
  }
  float* p = partial + (size_t)blockIdx.y * 128 * N;
  #pragma unroll
  for (int i = 0; i < 8; ++i) {
    #pragma unroll
    for (int jj = 0; jj < 4; ++jj) {
      const int cc = n0 + c0 + jj;
      if (cc < N) p[(r0 + i) * N + cc] = acc[i][jj];
    }
  }
}

// ---------------- reduce split-K partials + bias + relu + bn ----------------
__global__ __launch_bounds__(256) void mlpred_kernel(
    const float* __restrict__ partial, int S, int N,
    const float* __restrict__ bias, const float* __restrict__ gg,
    const float* __restrict__ bb, const float* __restrict__ mm,
    const float* __restrict__ vv, float* __restrict__ outz) {
  const int oi = blockIdx.x * 256 + threadIdx.x;
  if (oi >= 128 * N) return;
  float s = 0.0f;
  for (int p = 0; p < S; ++p) s += partial[(size_t)p * 128 * N + oi];
  const int c = oi % N;
  const float z = fmaxf(s + bias[c], 0.0f);
  outz[oi] = (z - mm[c]) * rsqrtf(vv[c] + 1e-5f) * gg[c] + bb[c];
}

// ---------------- big GEMM: d_out.h_gcn = z2 @ W3 + b3 + h_gcn_pre (RMW) ----------------
__global__ __launch_bounds__(256) void w3_kernel(
    const float* __restrict__ z2, const float* __restrict__ W3,
    const float* __restrict__ b3, float* __restrict__ outh) {
  __shared__ __align__(16) float At[128][52];
  __shared__ __align__(16) float Wt[50][64];
  const int tid = threadIdx.x;
  const int n0 = blockIdx.x * 64;
  const int cg = tid & 15, rg = tid >> 4;
  const int c0 = cg * 4, r0 = rg * 8;
  float acc[8][4];
  #pragma unroll
  for (int i = 0; i < 8; ++i)
    #pragma unroll
    for (int jj = 0; jj < 4; ++jj) acc[i][jj] = 0.0f;
  for (int k0 = 0; k0 < 500; k0 += 50) {
    for (int idx = tid; idx < 128 * 50; idx += 256) {
      int r = idx / 50, kk = idx % 50;
      At[r][kk] = z2[r * 500 + k0 + kk];
    }
    for (int idx = tid; idx < 50 * 64; idx += 256) {
      int kk = idx >> 6, cc2 = idx & 63;
      Wt[kk][cc2] = W3[(size_t)(k0 + kk) * cKL32 + n0 + cc2];
    }
    __syncthreads();
    for (int kk = 0; kk < 50; kk += 2) {
      const float4 wv0 = *reinterpret_cast<const float4*>(&Wt[kk][c0]);
      const float4 wv1 = *reinterpret_cast<const float4*>(&Wt[kk + 1][c0]);
      #pragma unroll
      for (int i = 0; i < 8; ++i) {
        const float2 av = *reinterpret_cast<const float2*>(&At[r0 + i][kk]);
        acc[i][0] += av.x * wv0.x + av.y * wv1.x;
        acc[i][1] += av.x * wv0.y + av.y * wv1.y;
        acc[i][2] += av.x * wv0.z + av.y * wv1.z;
        acc[i][3] += av.x * wv0.w + av.y * wv1.w;
      }
    }
    __syncthreads();
  }
  #pragma unroll
  for (int i = 0; i < 8; ++i) {
    const int r = r0 + i;
    const size_t base = (size_t)r * cKL32 + n0 + c0;
    #pragma unroll
    for (int jj = 0; jj < 4; ++jj) {
      const int n = n0 + c0 + jj;
      outh[base + jj] = acc[i][jj] + b3[n] + outh[base + jj];
    }
  }
}

// ---------------- ann GEMM split-K ----------------
__global__ __launch_bounds__(256) void ann_kernel(
    const float* __restrict__ hg, const float* __restrict__ annW, float* __restrict__ partial) {
  __shared__ __align__(16) float At[128][34];
  __shared__ __align__(16) float Wt[32][128];
  const int tid = threadIdx.x;
  const int bx = blockIdx.x;   // 255
  const int k0 = bx * 384;
  const int cg = tid & 15, rg = tid >> 4;
  const int c0 = cg * 8, r0 = rg * 8;
  float acc[8][8];
  #pragma unroll
  for (int i = 0; i < 8; ++i)
    #pragma unroll
    for (int jj = 0; jj < 8; ++jj) acc[i][jj] = 0.0f;
  for (int st = 0; st < 12; ++st) {
    const int kb = k0 + st * 32;
    for (int idx = tid; idx < 128 * 32; idx += 256) {
      int r = idx >> 5, kk = idx & 31;
      At[r][kk] = hg[(size_t)r * cKL32 + kb + kk];
    }
    for (int idx = tid; idx < 32 * 128; idx += 256) {
      int kk = idx >> 7, cc2 = idx & 127;
      Wt[kk][cc2] = (cc2 < 100) ? annW[(size_t)(kb + kk) * 100 + cc2] : 0.0f;
    }
    __syncthreads();
    for (int kk = 0; kk < 32; kk += 2) {
      const float4 w00 = *reinterpret_cast<const float4*>(&Wt[kk][c0]);
      const float4 w01 = *reinterpret_cast<const float4*>(&Wt[kk][c0 + 4]);
      const float4 w10 = *reinterpret_cast<const float4*>(&Wt[kk + 1][c0]);
      const float4 w11 = *reinterpret_cast<const float4*>(&Wt[kk + 1][c0 + 4]);
      #pragma unroll
      for (int i = 0; i < 8; ++i) {
        const float2 av = *reinterpret_cast<const float2*>(&At[r0 + i][kk]);
        acc[i][0] += av.x * w00.x + av.y * w10.x;
        acc[i][1] += av.x * w00.y + av.y * w10.y;
        acc[i][2] += av.x * w00.z + av.y * w10.z;
        acc[i][3] += av.x * w00.w + av.y * w10.w;
        acc[i][4] += av.x * w01.x + av.y * w11.x;
        acc[i][5] += av.x * w01.y + av.y * w11.y;
        acc[i][6] += av.x * w01.z + av.y * w11.z;
        acc[i][7] += av.x * w01.w + av.y * w11.w;
      }
    }
    __syncthreads();
  }
  #pragma unroll
  for (int i = 0; i < 8; ++i) {
    #pragma unroll
    for (int jj = 0; jj < 8; ++jj) {
      const int cc = c0 + jj;
      if (cc < 100) partial[(size_t)bx * 12800 + (r0 + i) * 100 + cc] = acc[i][jj];
    }
  }
}

__global__ __launch_bounds__(256) void annred_kernel(
    const float* __restrict__ partial, const float* __restrict__ ab,
    const float* __restrict__ gg, const float* __restrict__ bb,
    const float* __restrict__ mm, const float* __restrict__ vv, float* __restrict__ hid) {
  const int oi = blockIdx.x * 256 + threadIdx.x;   // < 12800
  if (oi < 12800) {
    float s = 0.0f;
    for (int p = 0; p < 255; ++p) s += partial[(size_t)p * 12800 + oi];
    const int c = oi % 100;
    const float z = fmaxf(s + ab[c], 0.0f);
    hid[oi] = (z - mm[c]) * rsqrtf(vv[c] + 1e-5f) * gg[c] + bb[c];
  }
}

// ---------------- log_prob: MAF collapses to u = a*x + b (mask_out all zeros) ----------------
__global__ __launch_bounds__(256) void logp_kernel(
    const float* __restrict__ x, const float* __restrict__ mob,
    const float* __restrict__ mlg, const float* __restrict__ mbeta, float* __restrict__ lp) {
  const int b = blockIdx.x;
  const int tid = threadIdx.x;
  const float rs = rsqrtf(1.0f + 1e-5f);
  const float A0 = __expf(mlg[0] - mob[1]) * rs;
  const float B0 = -mob[0] * __expf(-mob[1]) * __expf(mlg[0]) * rs + mbeta[0];
  const float A1 = __expf(mlg[1] - mob[3]) * rs;
  const float B1 = -mob[2] * __expf(-mob[3]) * __expf(mlg[1]) * rs + mbeta[1];
  const float S = (mlg[0] - mob[1]) + (mlg[1] - mob[3]) - logf(1.0f + 1e-5f);
  const float a = A1 * A0;
  const float bc = A1 * B0 + B1;
  float s = 0.0f;
  for (int t = tid; t < cKL; t += 256) {
    const float u = a * x[b * cKL + t] + bc;
    s += u * u;
  }
  #pragma unroll
  for (int off = 32; off > 0; off >>= 1) s += __shfl_down(s, off);
  __shared__ float red[4];
  if ((tid & 63) == 0) red[tid >> 6] = s;
  __syncthreads();
  if (tid == 0) {
    const float tot = red[0] + red[1] + red[2] + red[3];
    lp[b] = -0.5f * tot / (float)cKL + (-0.5f * kLOG2PI + S);
  }
}

__global__ void lpmean_kernel(const float* __restrict__ lp, float* __restrict__ outm) {
  __shared__ float red[128];
  const int tid = threadIdx.x;
  red[tid] = lp[tid];
  __syncthreads();
  for (int off = 64; off > 0; off >>= 1) {
    if (tid < off) red[tid] += red[tid + off];
    __syncthreads();
  }
  if (tid == 0) outm[0] = red[0] / 128.0f;
}

extern "C" void kernel_launch(void* const* d_in, const int* in_sizes, int n_in,
                              void* d_out, int out_size, void* d_ws, size_t ws_size,
                              hipStream_t stream) {
  const float* x    = (const float*)d_in[0];
  const float* Wq   = (const float*)d_in[1];
  const float* bq   = (const float*)d_in[2];
  const float* Wk   = (const float*)d_in[3];
  const float* bk   = (const float*)d_in[4];
  const float* Wih  = (const float*)d_in[5];
  const float* Whh  = (const float*)d_in[6];
  const float* bih  = (const float*)d_in[7];
  const float* bhh  = (const float*)d_in[8];
  const float* gWn  = (const float*)d_in[9];
  const float* gbn  = (const float*)d_in[10];
  const float* gWr  = (const float*)d_in[11];
  const float* gW2  = (const float*)d_in[12];
  const float* gb2  = (const float*)d_in[13];
  const float* W1   = (const float*)d_in[14];
  const float* b1   = (const float*)d_in[15];
  const float* bn1g = (const float*)d_in[16];
  const float* bn1b = (const float*)d_in[17];
  const float* bn1m = (const float*)d_in[18];
  const float* bn1v = (const float*)d_in[19];
  const float* W2m  = (const float*)d_in[20];
  const float* b2m  = (const float*)d_in[21];
  const float* bn2g = (const float*)d_in[22];
  const float* bn2b = (const float*)d_in[23];
  const float* bn2m = (const float*)d_in[24];
  const float* bn2v = (const float*)d_in[25];
  const float* W3   = (const float*)d_in[26];
  const float* b3   = (const float*)d_in[27];
  const float* annW = (const float*)d_in[28];
  const float* annb = (const float*)d_in[29];
  const float* abg  = (const float*)d_in[30];
  const float* abb  = (const float*)d_in[31];
  const float* abm  = (const float*)d_in[32];
  const float* abv  = (const float*)d_in[33];
  const float* mob  = (const float*)d_in[38];
  const float* mlg  = (const float*)d_in[39];
  const float* mbeta= (const float*)d_in[40];

  float* ws = (float*)d_ws;
  float* qb    = ws;                    // 391680
  float* kb    = ws + 391680;           // 391680
  float* graph = ws + 783360;           // 332928
  float* hbuf  = ws + 1116288;          // 12533760
  float* z1    = ws + 13650048;         // 64000
  float* z2    = ws + 13714048;         // 64000  (total 13778048 floats = 55.1 MB)
  float* partial = hbuf;                // ann split-K partials (hbuf dead by then)
  float* mp    = hbuf + 4000000;        // mlp split-K partials

  float* outF = (float*)d_out;
  float* hid  = outF;                   // 12800
  float* lpm  = outF + 12800;           // 1
  float* hgcn = outF + 12801;           // 12533760
  float* lp   = outF + 12546561;        // 128

  qk_kernel<<<816, 256, 0, stream>>>(x, Wq, bq, Wk, bk, qb, kb);
  attn_kernel<<<128, 256, 0, stream>>>(qb, kb, graph);
  lstm_kernel<<<1632, 256, 0, stream>>>(x, Wih, Whh, bih, bhh, hbuf);
  agg_kernel<<<dim3(15, 128), 256, 0, stream>>>(hbuf, graph, hgcn);
  gnn2_kernel<<<2040, 256, 0, stream>>>(hbuf, gWn, gbn, gWr, gW2, gb2, hgcn);
  gemm_splitk_kernel<<<dim3(8, 48), 256, 0, stream>>>(x, W1, 3060, 500, mp);
  mlpred_kernel<<<250, 256, 0, stream>>>(mp, 48, 500, b1, bn1g, bn1b, bn1m, bn1v, z1);
  gemm_splitk_kernel<<<dim3(8, 8), 256, 0, stream>>>(z1, W2m, 500, 500, mp);
  mlpred_kernel<<<250, 256, 0, stream>>>(mp, 8, 500, b2m, bn2g, bn2b, bn2m, bn2v, z2);
  w3_kernel<<<1530, 256, 0, stream>>>(z2, W3, b3, hgcn);
  ann_kernel<<<255, 256, 0, stream>>>(hgcn, annW, partial);
  annred_kernel<<<50, 256, 0, stream>>>(partial, annb, abg, abb, abm, abv, hid);
  logp_kernel<<<128, 256, 0, stream>>>(x, mob, mlg, mbeta, lp);
  lpmean_kernel<<<1, 128, 0, stream>>>(lp, lpm);
}

// Round 4
// 1188.388 us; speedup vs baseline: 1.7903x; 1.0064x over previous
//
#include <hip/hip_runtime.h>
#include <math.h>

constexpr int cB = 128;
constexpr int cK = 51;
constexpr int cL = 60;
constexpr int cH = 32;
constexpr int cC = 60;           // L*D
constexpr int cKL = 3060;        // K*L
constexpr int cKL32 = 97920;     // K*L*32
constexpr float kLOG2PI = 1.8378770664093453f;

typedef __attribute__((ext_vector_type(8))) short bfrag8;    // 8 bf16 = 4 VGPRs
typedef __attribute__((ext_vector_type(16))) float accf16;   // MFMA 32x32 accumulator

__device__ __forceinline__ float fsig(float x) { return 1.0f / (1.0f + __expf(-x)); }
__device__ __forceinline__ float ftanh(float x) {
  float e = __expf(2.0f * x);
  return 1.0f - 2.0f / (e + 1.0f);
}
__device__ __forceinline__ short f2bf(float f) {   // RNE fp32 -> bf16
  union { float f; unsigned u; } v; v.f = f;
  unsigned r = v.u + 0x7FFFu + ((v.u >> 16) & 1u);
  return (short)(r >> 16);
}

// ---------------- q/k projections: rows = B*K = 6528, 8 rows/block ----------------
__global__ __launch_bounds__(256) void qk_kernel(
    const float* __restrict__ x, const float* __restrict__ Wq, const float* __restrict__ bq,
    const float* __restrict__ Wk, const float* __restrict__ bk,
    float* __restrict__ q, float* __restrict__ kx) {
  __shared__ float xs[8][cC];
  const int row0 = blockIdx.x * 8;
  const int tid = threadIdx.x;
  for (int idx = tid; idx < 8 * cC; idx += 256) {
    int lr = idx / cC, t = idx % cC;
    xs[lr][t] = x[(row0 + lr) * cC + t];
  }
  __syncthreads();
  for (int idx = tid; idx < 8 * 2 * cC; idx += 256) {
    int col = idx % cC;
    int r2 = idx / cC;
    int m = r2 & 1, lr = r2 >> 1;
    const float* W = m ? Wk : Wq;
    float acc = m ? bk[col] : bq[col];
    #pragma unroll 4
    for (int t = 0; t < cC; ++t) acc += xs[lr][t] * W[t * cC + col];
    float* outp = m ? kx : q;
    outp[(row0 + lr) * cC + col] = acc;
  }
}

// ---------------- score = q @ reshape(k) / sqrt(60); softmax over axis=1 ----------------
__global__ __launch_bounds__(256) void attn_kernel(
    const float* __restrict__ q, const float* __restrict__ kx, float* __restrict__ graph) {
  __shared__ float qb[cKL];
  __shared__ float kb[cKL];
  __shared__ float sc[cK * cK];
  __shared__ float cmax[cK], csum[cK];
  const int b = blockIdx.x;
  const int tid = threadIdx.x;
  for (int idx = tid; idx < cKL; idx += 256) {
    qb[idx] = q[b * cKL + idx];
    kb[idx] = kx[b * cKL + idx];
  }
  __syncthreads();
  const float scale = 1.0f / sqrtf(60.0f);
  for (int idx = tid; idx < cK * cK; idx += 256) {
    int i = idx / cK, j = idx % cK;
    float acc = 0.0f;
    #pragma unroll 4
    for (int t = 0; t < cC; ++t) acc += qb[i * cC + t] * kb[t * cK + j];
    sc[idx] = acc * scale;
  }
  __syncthreads();
  if (tid < cK) {
    float m = -1e30f;
    for (int i = 0; i < cK; ++i) m = fmaxf(m, sc[i * cK + tid]);
    float ssum = 0.0f;
    for (int i = 0; i < cK; ++i) ssum += __expf(sc[i * cK + tid] - m);
    cmax[tid] = m; csum[tid] = ssum;
  }
  __syncthreads();
  for (int idx = tid; idx < cK * cK; idx += 256) {
    int j = idx % cK;
    graph[b * cK * cK + idx] = __expf(sc[idx] - cmax[j]) / csum[j];
  }
}

// ---------------- LSTM: one wave (64 lanes) per sequence, 4 sequences/block ----------------
__global__ __launch_bounds__(256) void lstm_kernel(
    const float* __restrict__ x, const float* __restrict__ Wih, const float* __restrict__ Whh,
    const float* __restrict__ bih, const float* __restrict__ bhh, float* __restrict__ hout) {
  const int wave = threadIdx.x >> 6;
  const int lane = threadIdx.x & 63;
  const int seq = blockIdx.x * 4 + wave;   // < 6528
  const int j = lane;
  float w0[32], w1[32];
  #pragma unroll
  for (int k2 = 0; k2 < 32; ++k2) {
    w0[k2] = Whh[j * 32 + k2];
    w1[k2] = Whh[(j + 64) * 32 + k2];
  }
  const float wi0 = Wih[j], wi1 = Wih[j + 64];
  const float bb0 = bih[j] + bhh[j];
  const float bb1 = bih[j + 64] + bhh[j + 64];
  const float xr = (lane < cL) ? x[seq * cL + lane] : 0.0f;
  float h = 0.0f, c = 0.0f;
  float* outp = hout + (size_t)seq * cL * cH;
  for (int t = 0; t < cL; ++t) {
    const float xt = __shfl(xr, t);
    float a0 = bb0 + wi0 * xt;
    float a1 = bb1 + wi1 * xt;
    #pragma unroll
    for (int k2 = 0; k2 < 32; ++k2) {
      const float hk = __shfl(h, k2);
      a0 += w0[k2] * hk;
      a1 += w1[k2] * hk;
    }
    const float sA = fsig(a0);
    const float sB = fsig(a1);
    const float tB = ftanh(a1);
    const float p = sA * tB;
    const float sf = __shfl(sA, (lane & 31) + 32);
    const float so = __shfl(sB, (lane & 31) + 32);
    c = sf * c + p;
    h = so * ftanh(c);
    if (lane < 32) outp[t * cH + lane] = h;
  }
}

// ---------------- agg: per b, agg = G^T (51x51) @ H (51x1920), 128-col tiles ----------------
__global__ __launch_bounds__(256) void agg_kernel(
    const float* __restrict__ hbuf, const float* __restrict__ graph,
    float* __restrict__ aggout) {
  __shared__ float G[cK * cK];
  __shared__ __align__(16) float Ht[cK][128];
  const int b = blockIdx.y;
  const int c0 = blockIdx.x * 128;
  const int tid = threadIdx.x;
  for (int idx = tid; idx < cK * cK; idx += 256) G[idx] = graph[b * cK * cK + idx];
  for (int idx = tid; idx < cK * 128; idx += 256) {
    int k = idx >> 7, c = idx & 127;
    Ht[k][c] = hbuf[((size_t)b * cK + k) * 1920 + c0 + c];
  }
  __syncthreads();
  const int jg = tid >> 5;
  const int cg = tid & 31;
  const int cc = cg * 4;
  float4 acc[7];
  #pragma unroll
  for (int jj = 0; jj < 7; ++jj) acc[jj] = make_float4(0.f, 0.f, 0.f, 0.f);
  for (int k = 0; k < cK; ++k) {
    const float4 hv = *reinterpret_cast<const float4*>(&Ht[k][cc]);
    #pragma unroll
    for (int jj = 0; jj < 7; ++jj) {
      const int j = jg + jj * 8;
      const float g = (j < cK) ? G[k * cK + j] : 0.0f;
      acc[jj].x += g * hv.x; acc[jj].y += g * hv.y;
      acc[jj].z += g * hv.z; acc[jj].w += g * hv.w;
    }
  }
  #pragma unroll
  for (int jj = 0; jj < 7; ++jj) {
    const int j = jg + jj * 8;
    if (j < cK) {
      const size_t o = ((size_t)b * cK + j) * 1920 + c0 + cc;
      aggout[o + 0] = acc[jj].x; aggout[o + 1] = acc[jj].y;
      aggout[o + 2] = acc[jj].z; aggout[o + 3] = acc[jj].w;
    }
  }
}

// ---------------- gnn2: per-row h_gcn_pre = relu(agg@Wn + bn + hm@Wr) @ W2 + b2 ----------------
__global__ __launch_bounds__(256) void gnn2_kernel(
    const float* __restrict__ hbuf, const float* __restrict__ Wn,
    const float* __restrict__ bn_, const float* __restrict__ Wr,
    const float* __restrict__ W2, const float* __restrict__ b2,
    float* __restrict__ hg) {
  __shared__ __align__(16) float wn[cH * cH];
  __shared__ __align__(16) float wr[cH * cH];
  __shared__ __align__(16) float w2[cH * cH];
  __shared__ float bnb[cH], b2b[cH];
  __shared__ float A_[192][33];
  __shared__ float M_[192][33];
  const int tid = threadIdx.x;
  const int row0 = blockIdx.x * 192;
  for (int idx = tid; idx < cH * cH; idx += 256) { wn[idx] = Wn[idx]; wr[idx] = Wr[idx]; w2[idx] = W2[idx]; }
  if (tid < cH) { bnb[tid] = bn_[tid]; b2b[tid] = b2[tid]; }
  for (int idx = tid; idx < 192 * 32; idx += 256) {
    const int r = idx >> 5, d = idx & 31;
    A_[r][d] = hg[(size_t)(row0 + r) * 32 + d];
    const int g = row0 + r;
    const int l = g % 60;
    M_[r][d] = (l > 0) ? hbuf[(size_t)(g - 1) * 32 + d] : 0.0f;
  }
  __syncthreads();
  const int rg = tid >> 2;
  const int cg = tid & 3;
  const int c0 = cg * 8;
  const int r0 = rg * 3;
  float acc[3][8];
  #pragma unroll
  for (int i = 0; i < 3; ++i)
    #pragma unroll
    for (int d = 0; d < 8; ++d) acc[i][d] = bnb[c0 + d];
  for (int e = 0; e < cH; ++e) {
    const float4 wn0 = *reinterpret_cast<const float4*>(&wn[e * cH + c0]);
    const float4 wn1 = *reinterpret_cast<const float4*>(&wn[e * cH + c0 + 4]);
    const float4 wr0 = *reinterpret_cast<const float4*>(&wr[e * cH + c0]);
    const float4 wr1 = *reinterpret_cast<const float4*>(&wr[e * cH + c0 + 4]);
    #pragma unroll
    for (int i = 0; i < 3; ++i) {
      const float a = A_[r0 + i][e];
      const float m = M_[r0 + i][e];
      acc[i][0] += a * wn0.x + m * wr0.x; acc[i][1] += a * wn0.y + m * wr0.y;
      acc[i][2] += a * wn0.z + m * wr0.z; acc[i][3] += a * wn0.w + m * wr0.w;
      acc[i][4] += a * wn1.x + m * wr1.x; acc[i][5] += a * wn1.y + m * wr1.y;
      acc[i][6] += a * wn1.z + m * wr1.z; acc[i][7] += a * wn1.w + m * wr1.w;
    }
  }
  __syncthreads();
  #pragma unroll
  for (int i = 0; i < 3; ++i)
    #pragma unroll
    for (int d = 0; d < 8; ++d) A_[r0 + i][c0 + d] = fmaxf(acc[i][d], 0.0f);
  __syncthreads();
  float acc2[3][8];
  #pragma unroll
  for (int i = 0; i < 3; ++i)
    #pragma unroll
    for (int d = 0; d < 8; ++d) acc2[i][d] = b2b[c0 + d];
  for (int e = 0; e < cH; ++e) {
    const float4 w20 = *reinterpret_cast<const float4*>(&w2[e * cH + c0]);
    const float4 w21 = *reinterpret_cast<const float4*>(&w2[e * cH + c0 + 4]);
    #pragma unroll
    for (int i = 0; i < 3; ++i) {
      const float t = A_[r0 + i][e];
      acc2[i][0] += t * w20.x; acc2[i][1] += t * w20.y;
      acc2[i][2] += t * w20.z; acc2[i][3] += t * w20.w;
      acc2[i][4] += t * w21.x; acc2[i][5] += t * w21.y;
      acc2[i][6] += t * w21.z; acc2[i][7] += t * w21.w;
    }
  }
  #pragma unroll
  for (int i = 0; i < 3; ++i)
    #pragma unroll
    for (int d = 0; d < 8; ++d) M_[r0 + i][c0 + d] = acc2[i][d];
  __syncthreads();
  for (int idx = tid; idx < 192 * 32; idx += 256) {
    const int r = idx >> 5, d = idx & 31;
    hg[(size_t)row0 * 32 + idx] = M_[r][d];
  }
}

// ---------------- split-K GEMM (fp32, small): partial[s] = A[:, ks:+64] @ W[ks:+64, n0:+64] ----------------
__global__ __launch_bounds__(256) void gemm_splitk_kernel(
    const float* __restrict__ A, const float* __restrict__ W,
    int K, int N, float* __restrict__ partial) {
  __shared__ __align__(16) float At[128][65];
  __shared__ __align__(16) float Wt[64][64];
  const int tid = threadIdx.x;
  const int n0 = blockIdx.x * 64;
  const int k0 = blockIdx.y * 64;
  const int kw = min(64, K - k0);
  for (int idx = tid; idx < 128 * 64; idx += 256) {
    int r = idx >> 6, kk = idx & 63;
    At[r][kk] = (kk < kw) ? A[(size_t)r * K + k0 + kk] : 0.0f;
  }
  for (int idx = tid; idx < 64 * 64; idx += 256) {
    int kk = idx >> 6, cc = idx & 63;
    Wt[kk][cc] = (kk < kw && n0 + cc < N) ? W[(size_t)(k0 + kk) * N + n0 + cc] : 0.0f;
  }
  __syncthreads();
  const int cg = tid & 15, rg = tid >> 4;
  const int c0 = cg * 4, r0 = rg * 8;
  float acc[8][4];
  #pragma unroll
  for (int i = 0; i < 8; ++i)
    #pragma unroll
    for (int jj = 0; jj < 4; ++jj) acc[i][jj] = 0.0f;
  for (int kk = 0; kk < 64; kk += 2) {
    const float4 wv0 = *reinterpret_cast<const float4*>(&Wt[kk][c0]);
    const float4 wv1 = *reinterpret_cast<const float4*>(&Wt[kk + 1][c0]);
    #pragma unroll
    for (int i = 0; i < 8; ++i) {
      const float2 av = *reinterpret_cast<const float2*>(&At[r0 + i][kk]);
      acc[i][0] += av.x * wv0.x + av.y * wv1.x;
      acc[i][1] += av.x * wv0.y + av.y * wv1.y;
      acc[i][2] += av.x * wv0.z + av.y * wv1.z;
      acc[i][3] += av.x * wv0.w + av.y * wv1.w;
    }
  }
  float* p = partial + (size_t)blockIdx.y * 128 * N;
  #pragma unroll
  for (int i = 0; i < 8; ++i) {
    #pragma unroll
    for (int jj = 0; jj < 4; ++jj) {
      const int cc = n0 + c0 + jj;
      if (cc < N) p[(r0 + i) * N + cc] = acc[i][jj];
    }
  }
}

__global__ __launch_bounds__(256) void mlpred_kernel(
    const float* __restrict__ partial, int S, int N,
    const float* __restrict__ bias, const float* __restrict__ gg,
    const float* __restrict__ bb, const float* __restrict__ mm,
    const float* __restrict__ vv, float* __restrict__ outz) {
  const int oi = blockIdx.x * 256 + threadIdx.x;
  if (oi >= 128 * N) return;
  float s = 0.0f;
  for (int p = 0; p < S; ++p) s += partial[(size_t)p * 128 * N + oi];
  const int c = oi % N;
  const float z = fmaxf(s + bias[c], 0.0f);
  outz[oi] = (z - mm[c]) * rsqrtf(vv[c] + 1e-5f) * gg[c] + bb[c];
}

// ---------------- big GEMM via bf16 MFMA: h_gcn += z2 @ W3 + b3 (RMW) ----------------
// Block = 4 waves; output 128 rows x 64 cols. v_mfma_f32_32x32x16_bf16.
// A-frag: A[m=lane&31][k=(lane>>5)*8+j]; B-frag: B[k][n=lane&31] same k map.
// C/D: col=lane&31, row=(reg&3)+8*(reg>>2)+4*(lane>>5)  [m74/m101 verified]
__global__ __launch_bounds__(256) void w3_mfma_kernel(
    const float* __restrict__ z2, const float* __restrict__ W3,
    const float* __restrict__ b3, float* __restrict__ outh) {
  __shared__ __align__(16) short As[128][40];   // 128 x 32 bf16, rows padded to 80B
  __shared__ __align__(16) short Bs[64][40];    // B^T: [n][k], 64 x 32 bf16
  const int tid = threadIdx.x;
  const int n0 = blockIdx.x * 64;
  const int wave = tid >> 6;
  const int lane = tid & 63;
  const int half = lane >> 5;
  const int lm = lane & 31;
  accf16 acc0 = {};
  accf16 acc1 = {};
  for (int kt = 0; kt < 16; ++kt) {
    const int k0 = kt * 32;
    {
      int r = tid >> 5;
      const int kk = tid & 31;
      const bool kv = (k0 + kk < 500);
      #pragma unroll
      for (int p = 0; p < 16; ++p, r += 8)
        As[r][kk] = kv ? f2bf(z2[r * 500 + k0 + kk]) : (short)0;
    }
    {
      int kk = tid >> 6;
      const int n = tid & 63;
      #pragma unroll
      for (int p = 0; p < 8; ++p, kk += 4) {
        const bool kv = (k0 + kk < 500);
        Bs[n][kk] = kv ? f2bf(W3[(size_t)(k0 + kk) * cKL32 + n0 + n]) : (short)0;
      }
    }
    __syncthreads();
    #pragma unroll
    for (int s = 0; s < 2; ++s) {
      const bfrag8 a  = *reinterpret_cast<const bfrag8*>(&As[wave * 32 + lm][s * 16 + half * 8]);
      const bfrag8 b0 = *reinterpret_cast<const bfrag8*>(&Bs[lm][s * 16 + half * 8]);
      const bfrag8 b1 = *reinterpret_cast<const bfrag8*>(&Bs[32 + lm][s * 16 + half * 8]);
      acc0 = __builtin_amdgcn_mfma_f32_32x32x16_bf16(a, b0, acc0, 0, 0, 0);
      acc1 = __builtin_amdgcn_mfma_f32_32x32x16_bf16(a, b1, acc1, 0, 0, 0);
    }
    __syncthreads();
  }
  const int r0w = wave * 32;
  const float bias0 = b3[n0 + lm];
  const float bias1 = b3[n0 + 32 + lm];
  #pragma unroll
  for (int reg = 0; reg < 16; ++reg) {
    const int rr = r0w + (reg & 3) + 8 * (reg >> 2) + 4 * half;
    const size_t o0 = (size_t)rr * cKL32 + n0 + lm;
    outh[o0] += acc0[reg] + bias0;
    outh[o0 + 32] += acc1[reg] + bias1;
  }
}

// ---------------- ann GEMM split-K ----------------
__global__ __launch_bounds__(256) void ann_kernel(
    const float* __restrict__ hg, const float* __restrict__ annW, float* __restrict__ partial) {
  __shared__ __align__(16) float At[128][34];
  __shared__ __align__(16) float Wt[32][128];
  const int tid = threadIdx.x;
  const int bx = blockIdx.x;   // 255
  const int k0 = bx * 384;
  const int cg = tid & 15, rg = tid >> 4;
  const int c0 = cg * 8, r0 = rg * 8;
  float acc[8][8];
  #pragma unroll
  for (int i = 0; i < 8; ++i)
    #pragma unroll
    for (int jj = 0; jj < 8; ++jj) acc[i][jj] = 0.0f;
  for (int st = 0; st < 12; ++st) {
    const int kb = k0 + st * 32;
    for (int idx = tid; idx < 128 * 32; idx += 256) {
      int r = idx >> 5, kk = idx & 31;
      At[r][kk] = hg[(size_t)r * cKL32 + kb + kk];
    }
    for (int idx = tid; idx < 32 * 128; idx += 256) {
      int kk = idx >> 7, cc2 = idx & 127;
      Wt[kk][cc2] = (cc2 < 100) ? annW[(size_t)(kb + kk) * 100 + cc2] : 0.0f;
    }
    __syncthreads();
    for (int kk = 0; kk < 32; kk += 2) {
      const float4 w00 = *reinterpret_cast<const float4*>(&Wt[kk][c0]);
      const float4 w01 = *reinterpret_cast<const float4*>(&Wt[kk][c0 + 4]);
      const float4 w10 = *reinterpret_cast<const float4*>(&Wt[kk + 1][c0]);
      const float4 w11 = *reinterpret_cast<const float4*>(&Wt[kk + 1][c0 + 4]);
      #pragma unroll
      for (int i = 0; i < 8; ++i) {
        const float2 av = *reinterpret_cast<const float2*>(&At[r0 + i][kk]);
        acc[i][0] += av.x * w00.x + av.y * w10.x;
        acc[i][1] += av.x * w00.y + av.y * w10.y;
        acc[i][2] += av.x * w00.z + av.y * w10.z;
        acc[i][3] += av.x * w00.w + av.y * w10.w;
        acc[i][4] += av.x * w01.x + av.y * w11.x;
        acc[i][5] += av.x * w01.y + av.y * w11.y;
        acc[i][6] += av.x * w01.z + av.y * w11.z;
        acc[i][7] += av.x * w01.w + av.y * w11.w;
      }
    }
    __syncthreads();
  }
  #pragma unroll
  for (int i = 0; i < 8; ++i) {
    #pragma unroll
    for (int jj = 0; jj < 8; ++jj) {
      const int cc = c0 + jj;
      if (cc < 100) partial[(size_t)bx * 12800 + (r0 + i) * 100 + cc] = acc[i][jj];
    }
  }
}

__global__ __launch_bounds__(256) void annred_kernel(
    const float* __restrict__ partial, const float* __restrict__ ab,
    const float* __restrict__ gg, const float* __restrict__ bb,
    const float* __restrict__ mm, const float* __restrict__ vv, float* __restrict__ hid) {
  const int oi = blockIdx.x * 256 + threadIdx.x;   // < 12800
  if (oi < 12800) {
    float s = 0.0f;
    for (int p = 0; p < 255; ++p) s += partial[(size_t)p * 12800 + oi];
    const int c = oi % 100;
    const float z = fmaxf(s + ab[c], 0.0f);
    hid[oi] = (z - mm[c]) * rsqrtf(vv[c] + 1e-5f) * gg[c] + bb[c];
  }
}

// ---------------- log_prob: MAF collapses to u = a*x + b (mask_out all zeros) ----------------
__global__ __launch_bounds__(256) void logp_kernel(
    const float* __restrict__ x, const float* __restrict__ mob,
    const float* __restrict__ mlg, const float* __restrict__ mbeta, float* __restrict__ lp) {
  const int b = blockIdx.x;
  const int tid = threadIdx.x;
  const float rs = rsqrtf(1.0f + 1e-5f);
  const float A0 = __expf(mlg[0] - mob[1]) * rs;
  const float B0 = -mob[0] * __expf(-mob[1]) * __expf(mlg[0]) * rs + mbeta[0];
  const float A1 = __expf(mlg[1] - mob[3]) * rs;
  const float B1 = -mob[2] * __expf(-mob[3]) * __expf(mlg[1]) * rs + mbeta[1];
  const float S = (mlg[0] - mob[1]) + (mlg[1] - mob[3]) - logf(1.0f + 1e-5f);
  const float a = A1 * A0;
  const float bc = A1 * B0 + B1;
  float s = 0.0f;
  for (int t = tid; t < cKL; t += 256) {
    const float u = a * x[b * cKL + t] + bc;
    s += u * u;
  }
  #pragma unroll
  for (int off = 32; off > 0; off >>= 1) s += __shfl_down(s, off);
  __shared__ float red[4];
  if ((tid & 63) == 0) red[tid >> 6] = s;
  __syncthreads();
  if (tid == 0) {
    const float tot = red[0] + red[1] + red[2] + red[3];
    lp[b] = -0.5f * tot / (float)cKL + (-0.5f * kLOG2PI + S);
  }
}

__global__ void lpmean_kernel(const float* __restrict__ lp, float* __restrict__ outm) {
  __shared__ float red[128];
  const int tid = threadIdx.x;
  red[tid] = lp[tid];
  __syncthreads();
  for (int off = 64; off > 0; off >>= 1) {
    if (tid < off) red[tid] += red[tid + off];
    __syncthreads();
  }
  if (tid == 0) outm[0] = red[0] / 128.0f;
}

extern "C" void kernel_launch(void* const* d_in, const int* in_sizes, int n_in,
                              void* d_out, int out_size, void* d_ws, size_t ws_size,
                              hipStream_t stream) {
  const float* x    = (const float*)d_in[0];
  const float* Wq   = (const float*)d_in[1];
  const float* bq   = (const float*)d_in[2];
  const float* Wk   = (const float*)d_in[3];
  const float* bk   = (const float*)d_in[4];
  const float* Wih  = (const float*)d_in[5];
  const float* Whh  = (const float*)d_in[6];
  const float* bih  = (const float*)d_in[7];
  const float* bhh  = (const float*)d_in[8];
  const float* gWn  = (const float*)d_in[9];
  const float* gbn  = (const float*)d_in[10];
  const float* gWr  = (const float*)d_in[11];
  const float* gW2  = (const float*)d_in[12];
  const float* gb2  = (const float*)d_in[13];
  const float* W1   = (const float*)d_in[14];
  const float* b1   = (const float*)d_in[15];
  const float* bn1g = (const float*)d_in[16];
  const float* bn1b = (const float*)d_in[17];
  const float* bn1m = (const float*)d_in[18];
  const float* bn1v = (const float*)d_in[19];
  const float* W2m  = (const float*)d_in[20];
  const float* b2m  = (const float*)d_in[21];
  const float* bn2g = (const float*)d_in[22];
  const float* bn2b = (const float*)d_in[23];
  const float* bn2m = (const float*)d_in[24];
  const float* bn2v = (const float*)d_in[25];
  const float* W3   = (const float*)d_in[26];
  const float* b3   = (const float*)d_in[27];
  const float* annW = (const float*)d_in[28];
  const float* annb = (const float*)d_in[29];
  const float* abg  = (const float*)d_in[30];
  const float* abb  = (const float*)d_in[31];
  const float* abm  = (const float*)d_in[32];
  const float* abv  = (const float*)d_in[33];
  const float* mob  = (const float*)d_in[38];
  const float* mlg  = (const float*)d_in[39];
  const float* mbeta= (const float*)d_in[40];

  float* ws = (float*)d_ws;
  float* qb    = ws;                    // 391680
  float* kb    = ws + 391680;           // 391680
  float* graph = ws + 783360;           // 332928
  float* hbuf  = ws + 1116288;          // 12533760
  float* z1    = ws + 13650048;         // 64000
  float* z2    = ws + 13714048;         // 64000
  float* partial = hbuf;                // ann split-K partials (hbuf dead by then)
  float* mp    = hbuf + 4000000;        // mlp split-K partials

  float* outF = (float*)d_out;
  float* hid  = outF;                   // 12800
  float* lpm  = outF + 12800;           // 1
  float* hgcn = outF + 12801;           // 12533760
  float* lp   = outF + 12546561;        // 128

  qk_kernel<<<816, 256, 0, stream>>>(x, Wq, bq, Wk, bk, qb, kb);
  attn_kernel<<<128, 256, 0, stream>>>(qb, kb, graph);
  lstm_kernel<<<1632, 256, 0, stream>>>(x, Wih, Whh, bih, bhh, hbuf);
  agg_kernel<<<dim3(15, 128), 256, 0, stream>>>(hbuf, graph, hgcn);
  gnn2_kernel<<<2040, 256, 0, stream>>>(hbuf, gWn, gbn, gWr, gW2, gb2, hgcn);
  gemm_splitk_kernel<<<dim3(8, 48), 256, 0, stream>>>(x, W1, 3060, 500, mp);
  mlpred_kernel<<<250, 256, 0, stream>>>(mp, 48, 500, b1, bn1g, bn1b, bn1m, bn1v, z1);
  gemm_splitk_kernel<<<dim3(8, 8), 256, 0, stream>>>(z1, W2m, 500, 500, mp);
  mlpred_kernel<<<250, 256, 0, stream>>>(mp, 8, 500, b2m, bn2g, bn2b, bn2m, bn2v, z2);
  w3_mfma_kernel<<<1530, 256, 0, stream>>>(z2, W3, b3, hgcn);
  ann_kernel<<<255, 256, 0, stream>>>(hgcn, annW, partial);
  annred_kernel<<<50, 256, 0, stream>>>(partial, annb, abg, abb, abm, abv, hid);
  logp_kernel<<<128, 256, 0, stream>>>(x, mob, mlg, mbeta, lp);
  lpmean_kernel<<<1, 128, 0, stream>>>(lp, lpm);
}